// Round 7
// baseline (9918.498 us; speedup 1.0000x reference)
//
#include <hip/hip_runtime.h>
#include <hip/hip_bf16.h>

typedef __hip_bfloat16 bf16;

constexpr int NN = 307, TT = 12, BB = 32, HH = 64, EE = 10, HEADS = 4, HD = 16, HORIZON = 12;

// ---------------- staged fp32 input offsets ----------------
constexpr int S_SRC = 0,       S_EMB = 117888,  S_GW0 = 120958,  S_GB0 = 287358,
              S_UW0 = 288638,  S_UB0 = 371838,  S_GW1 = 372478,  S_GB1 = 700158,
              S_UW1 = 701438,  S_UB1 = 865278,  S_MLW = 865918,  S_MLB = 865982,
              S_WQ  = 866046,  S_BQ  = 870142,  S_WK  = 870206,  S_BK  = 874302,
              S_WV  = 874366,  S_BV  = 878462,  S_WO  = 878526,  S_BO  = 882622,
              S_FW1 = 882686,  S_FB1 = 948222,  S_FW2 = 949246,  S_FB2 = 1014782,
              S_L1G = 1014846, S_L1B = 1014910, S_L2G = 1014974, S_L2B = 1015038,
              S_WS  = 1015102, S_WT  = 1034750, S_CW  = 1054398, S_CB  = 1055166;

// ---------------- fp32 work regions ----------------
constexpr size_t OFF_A    = 1055178;   // 307*307
constexpr size_t OFF_OUT0 = 1149427;   // [t][n][b][c] 12*307*2048
constexpr size_t OFF_H0   = 8694259;   // [n][b][c] 307*2048 (layer 0)
constexpr size_t OFF_ZH0  = 9322995;
constexpr size_t OFF_R0   = 9951731;
constexpr size_t OFF_AX0  = 11209203;  // [t][n][b] 12*307*32
constexpr size_t OFF_AX1  = 11327091;  // [t][n][b][c] 12*307*2048
constexpr size_t OFF_PE   = 18871923;  // 12*64
constexpr size_t OFF_OLN  = 18872691;
constexpr size_t OFF_O2   = 19501427;
constexpr size_t OFF_WB   = 20130164;  // fp32 reordered per-node GRU weights

// Reordered weight blocks (fp32; bf16 storage fails: scan amplifies to 0.19 absmax — r3)
constexpr size_t G0X = OFF_WB +        0;  // 307*2*128
constexpr size_t G0H = OFF_WB +    78592;  // 307*128*128
constexpr size_t BG0 = OFF_WB +  5108480;  // 307*128
constexpr size_t U0X = OFF_WB +  5147776;  // 307*2*64
constexpr size_t U0H = OFF_WB +  5187072;  // 307*128*64
constexpr size_t BU0 = OFF_WB +  7702016;  // 307*64
constexpr size_t G1X = OFF_WB +  7721664;  // 307*128*128
constexpr size_t G1H = OFF_WB + 12751552;  // 307*128*128
constexpr size_t BG1 = OFF_WB + 17781440;  // 307*128
constexpr size_t U1X = OFF_WB + 17820736;  // 307*128*64
constexpr size_t U1H = OFF_WB + 20335680;  // 307*128*64
constexpr size_t BU1 = OFF_WB + 22850624;  // 307*64
constexpr size_t OFF_GXP = OFF_WB + 22870272;       // [t][n][b][128] L0 preact x-part (bias folded)
constexpr size_t OFF_UXP = OFF_GXP + 15089664;      // [t][n][b][64]
constexpr size_t OFF_H1  = OFF_UXP + 7544832;       // layer-1 state buffers
constexpr size_t OFF_ZH1 = OFF_H1  + 628736;
constexpr size_t OFF_R1  = OFF_ZH1 + 628736;
constexpr size_t OFF_AGG0 = OFF_R1  + 628736;       // A@H (or A@ZH) per layer
constexpr size_t OFF_AGG1 = OFF_AGG0 + 628736;
constexpr size_t OFF_AT   = OFF_AGG1 + 628736;      // A^T (307*307), r16
constexpr size_t G_TOTAL  = OFF_AT + 94249 + 4096;

// r18->r19 post-mortem: r18 FAILED (absmax 0.27 == GRU branch never ran) —
// hipLaunchCooperativeKernel is illegal under the harness's hipGraph stream
// capture and its error code was ignored; k_scan never executed. Fallback as
// pre-committed: SAME megakernel, regular launch (capturable) + hand-rolled
// device-scope sense-reversing barrier. Grid 1024 = 4 blocks/CU exactly
// (launch_bounds(256,4) forces VGPR<=128; LDS 32KB -> 5/CU allowed) so all
// blocks are co-resident by resource math -> no deadlock window. Barrier:
// agent-scope atomic RMW chain (release sequence -> transitive visibility),
// RELAXED+s_sleep spin, trailing __threadfence. arrive reset BEFORE gen bump.
// Phase bodies bitwise identical to r17 -> absmax must return to 1.95e-3.

__device__ float g_buf[G_TOTAL];
__device__ int g_flag;   // 1 = inputs are bf16, 0 = fp32
__device__ unsigned g_bar_arrive;  // zero-init at module load; self-resetting
__device__ unsigned g_bar_gen;

__device__ __forceinline__ void grid_bar(unsigned nB) {
    __syncthreads();
    if (threadIdx.x == 0) {
        __threadfence();   // release this block's writes to device scope
        unsigned gen = __hip_atomic_load(&g_bar_gen, __ATOMIC_RELAXED, __HIP_MEMORY_SCOPE_AGENT);
        unsigned prev = __hip_atomic_fetch_add(&g_bar_arrive, 1u, __ATOMIC_ACQ_REL, __HIP_MEMORY_SCOPE_AGENT);
        if (prev + 1u == nB) {
            __hip_atomic_store(&g_bar_arrive, 0u, __ATOMIC_RELAXED, __HIP_MEMORY_SCOPE_AGENT);
            __hip_atomic_store(&g_bar_gen, gen + 1u, __ATOMIC_RELEASE, __HIP_MEMORY_SCOPE_AGENT);
        } else {
            while (__hip_atomic_load(&g_bar_gen, __ATOMIC_RELAXED, __HIP_MEMORY_SCOPE_AGENT) == gen) {
                __builtin_amdgcn_s_sleep(2);
            }
        }
        __threadfence();   // acquire remote writes
    }
    __syncthreads();
}

__device__ __forceinline__ float wave_sum(float v) {
    #pragma unroll
    for (int off = 32; off > 0; off >>= 1) v += __shfl_xor(v, off, 64);
    return v;
}

// ---------------- dtype detection ----------------
__global__ void k_detect(const void* emb_raw) {
    const bf16* p = (const bf16*)emb_raw;
    int lane = threadIdx.x;
    float v = __bfloat162float(p[lane]);
    bool plaus = (v == v) && (fabsf(v) <= 1e4f) && (v == 0.f || fabsf(v) >= 1e-4f);
    float c = wave_sum(plaus ? 1.f : 0.f);
    if (lane == 0) g_flag = (c >= 52.f) ? 1 : 0;
}

// ---------------- ingest all inputs as fp32 ----------------
struct PtrPack { const void* p[32]; };
__device__ const int D_CNT[32] = {117888,3070,166400,1280,83200,640,327680,1280,163840,640,
                                  64,64,4096,64,4096,64,4096,64,4096,64,
                                  65536,1024,65536,64,64,64,64,64,19648,19648,768,12};
__device__ const int D_OFF[32] = {S_SRC,S_EMB,S_GW0,S_GB0,S_UW0,S_UB0,S_GW1,S_GB1,S_UW1,S_UB1,
                                  S_MLW,S_MLB,S_WQ,S_BQ,S_WK,S_BK,S_WV,S_BV,S_WO,S_BO,
                                  S_FW1,S_FB1,S_FW2,S_FB2,S_L1G,S_L1B,S_L2G,S_L2B,S_WS,S_WT,S_CW,S_CB};
__device__ const int D_CHK[33] = {0,461,473,1123,1128,1453,1456,2736,2741,3381,3384,3385,3386,
                                  3402,3403,3419,3420,3436,3437,3453,3454,3710,3714,3970,3971,
                                  3972,3973,3974,3975,4052,4129,4132,4133};

__global__ void k_ingest(PtrPack pk) {
    int bid = blockIdx.x;
    int s = 0;
    while (s < 31 && bid >= D_CHK[s + 1]) s++;
    int i = (bid - D_CHK[s]) * 256 + threadIdx.x;
    if (i >= D_CNT[s]) return;
    float v;
    if (g_flag) v = __bfloat162float(((const bf16*)pk.p[s])[i]);
    else        v = ((const float*)pk.p[s])[i];
    g_buf[(size_t)D_OFF[s] + i] = v;
}

// ---------------- adjacency (also writes A^T for aggB staging — r16) ----------------
__global__ void k_adj() {
    int n = blockIdx.x;
    int tid = threadIdx.x;            // 512
    __shared__ float en[EE];
    __shared__ float red[512];
    if (tid < EE) en[tid] = g_buf[S_EMB + n * EE + tid];
    __syncthreads();
    bool act = tid < NN;
    float d = 0.f;
    if (act) {
        #pragma unroll
        for (int e = 0; e < EE; e++) d += en[e] * g_buf[S_EMB + tid * EE + e];
        d = fmaxf(d, 0.f);
    }
    red[tid] = act ? d : -1e30f;
    __syncthreads();
    for (int s = 256; s > 0; s >>= 1) { if (tid < s) red[tid] = fmaxf(red[tid], red[tid + s]); __syncthreads(); }
    float mx = red[0];
    __syncthreads();
    float ex = act ? expf(d - mx) : 0.f;
    red[tid] = ex;
    __syncthreads();
    for (int s = 256; s > 0; s >>= 1) { if (tid < s) red[tid] += red[tid + s]; __syncthreads(); }
    float inv = 1.f / red[0];
    if (act) {
        float av = ex * inv;
        g_buf[OFF_A  + (size_t)n * NN + tid] = av;       // A[n][m]
        g_buf[OFF_AT + (size_t)tid * NN + n] = av;       // AT[m][n]
    }
}

// ---------------- per-node GRU weights -> fp32, reordered into Wx/Wh blocks ----------------
// r14: 4 outputs/thread, compile-time divisors per segment, float4 stores.
__global__ void k_nodew_all() {
    unsigned i4 = blockIdx.x * 256u + threadIdx.x;
    if (i4 >= 5717568u) return;
    float a0 = 0.f, a1 = 0.f, a2 = 0.f, a3 = 0.f;
    size_t dst;
    unsigned n;

    #define NW_ACCUM(SRCOFF, JCONST) do {                                  \
        const float* eb = g_buf + S_EMB + n * EE;                          \
        const float* wp = g_buf + (SRCOFF) + j;                            \
        _Pragma("unroll")                                                  \
        for (int e = 0; e < EE; e++) {                                     \
            float ev = eb[e];                                              \
            a0 += ev * wp[0]; a1 += ev * wp[1];                            \
            a2 += ev * wp[2]; a3 += ev * wp[3];                            \
            wp += (JCONST);                                                \
        }                                                                  \
    } while (0)

    if (i4 < 1277120u) {               // s0: gw0, J=16640 (J4=4160)
        unsigned rem = i4;
        n = rem / 4160u;
        unsigned j = (rem - n * 4160u) * 4u;
        unsigned o = j & 127u, kk = j >> 7;
        unsigned k = (kk >= 65u) ? 1u : 0u, i = kk - k * 65u;
        dst = (i == 0u) ? G0X + ((size_t)(n * 2u + k)) * 128u + o
                        : G0H + ((size_t)(n * 128u + k * 64u + (i - 1u))) * 128u + o;
        NW_ACCUM(S_GW0, 16640u);
    } else if (i4 < 1286944u) {        // s1: gb0, J=128 (J4=32)
        unsigned rem = i4 - 1277120u;
        n = rem >> 5;
        unsigned j = (rem & 31u) * 4u;
        dst = BG0 + (size_t)n * 128u + j;
        NW_ACCUM(S_GB0, 128u);
    } else if (i4 < 1925504u) {        // s2: uw0, J=8320 (J4=2080)
        unsigned rem = i4 - 1286944u;
        n = rem / 2080u;
        unsigned j = (rem - n * 2080u) * 4u;
        unsigned o = j & 63u, kk = j >> 6;
        unsigned k = (kk >= 65u) ? 1u : 0u, i = kk - k * 65u;
        dst = (i == 0u) ? U0X + ((size_t)(n * 2u + k)) * 64u + o
                        : U0H + ((size_t)(n * 128u + k * 64u + (i - 1u))) * 64u + o;
        NW_ACCUM(S_UW0, 8320u);
    } else if (i4 < 1930416u) {        // s3: ub0, J=64 (J4=16)
        unsigned rem = i4 - 1925504u;
        n = rem >> 4;
        unsigned j = (rem & 15u) * 4u;
        dst = BU0 + (size_t)n * 64u + j;
        NW_ACCUM(S_UB0, 64u);
    } else if (i4 < 4445360u) {        // s4: gw1, J=32768 (J4=8192)
        unsigned rem = i4 - 1930416u;
        n = rem >> 13;
        unsigned j = (rem & 8191u) * 4u;
        unsigned o = j & 127u, kk = j >> 7;
        unsigned k = kk >> 7, i = kk & 127u;
        dst = (i < 64u) ? G1X + ((size_t)(n * 128u + k * 64u + i)) * 128u + o
                        : G1H + ((size_t)(n * 128u + k * 64u + (i - 64u))) * 128u + o;
        NW_ACCUM(S_GW1, 32768u);
    } else if (i4 < 4455184u) {        // s5: gb1, J=128 (J4=32)
        unsigned rem = i4 - 4445360u;
        n = rem >> 5;
        unsigned j = (rem & 31u) * 4u;
        dst = BG1 + (size_t)n * 128u + j;
        NW_ACCUM(S_GB1, 128u);
    } else if (i4 < 5712656u) {        // s6: uw1, J=16384 (J4=4096)
        unsigned rem = i4 - 4455184u;
        n = rem >> 12;
        unsigned j = (rem & 4095u) * 4u;
        unsigned o = j & 63u, kk = j >> 6;
        unsigned k = kk >> 7, i = kk & 127u;
        dst = (i < 64u) ? U1X + ((size_t)(n * 128u + k * 64u + i)) * 64u + o
                        : U1H + ((size_t)(n * 128u + k * 64u + (i - 64u))) * 64u + o;
        NW_ACCUM(S_UW1, 16384u);
    } else {                           // s7: ub1, J=64 (J4=16)
        unsigned rem = i4 - 5712656u;
        n = rem >> 4;
        unsigned j = (rem & 15u) * 4u;
        dst = BU1 + (size_t)n * 64u + j;
        NW_ACCUM(S_UB1, 64u);
    }
    #undef NW_ACCUM
    *(float4*)&g_buf[dst] = make_float4(a0, a1, a2, a3);
}

// ---------------- positional embedding ----------------
__global__ void k_pe() {
    int tid = threadIdx.x;            // 768
    int t = tid >> 6, h = tid & 63;
    float ex = (float)(h & ~1) / 64.f;
    float ang = (float)t * powf(10000.f, -ex);
    g_buf[OFF_PE + tid] = (h & 1) ? cosf(ang) : sinf(ang);
}

// ---------------- AX0[t][n][b] = sum_m A[n,m] * src[b,t,m] ----------------
__global__ __launch_bounds__(256) void k_ax0() {
    int t = blockIdx.y;
    int n0 = blockIdx.x * 8;
    int b = threadIdx.x & 31, nl = threadIdx.x >> 5;
    __shared__ float As[8][68];
    __shared__ float xs[32][65];
    float acc = 0.f;
    for (int m0 = 0; m0 < NN; m0 += 64) {
        int jend = min(64, NN - m0);
        for (int idx = threadIdx.x; idx < 8 * 64; idx += 256) {
            int i = idx >> 6, jj = idx & 63;
            int n = n0 + i, m = m0 + jj;
            As[i][jj] = (n < NN && m < NN) ? g_buf[OFF_A + (size_t)n * NN + m] : 0.f;
        }
        for (int idx = threadIdx.x; idx < 32 * 64; idx += 256) {
            int bb = idx >> 6, jj = idx & 63;
            int m = m0 + jj;
            xs[bb][jj] = (m < NN) ? g_buf[S_SRC + ((size_t)bb * TT + t) * NN + m] : 0.f;
        }
        __syncthreads();
        for (int jj = 0; jj < jend; jj++) acc += As[nl][jj] * xs[b][jj];
        __syncthreads();
    }
    int n = n0 + nl;
    if (n < NN) g_buf[OFF_AX0 + ((size_t)t * NN + n) * 32 + b] = acc;
}

// ---------------- x-part preact precompute, layer 0 (K=2); grid (12, NN) ----------------
__global__ __launch_bounds__(256) void k_xprep0() {
    int t = blockIdx.x, n = blockIdx.y, tid = threadIdx.x;
    __shared__ float xv[32], ax[32];
    if (tid < 32) {
        xv[tid] = g_buf[S_SRC + ((size_t)tid * TT + t) * NN + n];
        ax[tid] = g_buf[OFF_AX0 + ((size_t)t * NN + n) * 32 + tid];
    }
    __syncthreads();
    size_t pbase = ((size_t)t * NN + n) * 32;
    for (int idx = tid; idx < 4096; idx += 256) {
        int b = idx >> 7, o = idx & 127;
        g_buf[OFF_GXP + (pbase + b) * 128 + o] =
            g_buf[BG0 + (size_t)n * 128 + o]
          + g_buf[G0X + ((size_t)n * 2 + 0) * 128 + o] * xv[b]
          + g_buf[G0X + ((size_t)n * 2 + 1) * 128 + o] * ax[b];
    }
    for (int idx = tid; idx < 2048; idx += 256) {
        int b = idx >> 6, o = idx & 63;
        g_buf[OFF_UXP + (pbase + b) * 64 + o] =
            g_buf[BU0 + (size_t)n * 64 + o]
          + g_buf[U0X + ((size_t)n * 2 + 0) * 64 + o] * xv[b]
          + g_buf[U0X + ((size_t)n * 2 + 1) * 64 + o] * ax[b];
    }
}

// ================= scan megakernel phases (bodies = r17 verbatim) =================

__device__ __forceinline__ void agg_item(int s, int mode, int it, float* smem, int tid) {
    int z = it / 320;
    int rr = it - z * 320;
    int by = rr / 10;
    int bx = rr - by * 10;
    size_t srcOff, dstOff;
    float* __restrict__ dstp2 = nullptr;
    if (mode == 0) {
        if (z == 0) { srcOff = OFF_H0; dstOff = OFF_AGG0;
                      dstp2 = g_buf + OFF_AX1 + (size_t)(s - 1) * 628736; }
        else        { srcOff = OFF_H1; dstOff = OFF_AGG1; }
    } else {
        srcOff = z ? OFF_ZH1 : OFF_ZH0;
        dstOff = z ? OFF_AGG1 : OFF_AGG0;
    }
    const float* __restrict__ srcp = g_buf + srcOff;
    float* __restrict__ dstp = g_buf + dstOff;
    int n0 = bx * 32;
    int col0 = by * 64;
    int tn = tid >> 4, tc = tid & 15;       // i0 = tn*2, col = tc*4
    float* As = smem;                        // [64][34]
    float* Xs = smem + 2176;                 // [64][64]
    float acc[2][4];
    #pragma unroll
    for (int i = 0; i < 2; i++)
        #pragma unroll
        for (int j = 0; j < 4; j++) acc[i][j] = 0.f;
    for (int k0 = 0; k0 < NN; k0 += 64) {
        __syncthreads();   // prev chunk / prev item done with smem
        for (int idx = tid; idx < 64 * 32; idx += 256) {
            int i = idx & 31, k = idx >> 5;
            int n = n0 + i, m = k0 + k;
            As[k * 34 + i] = (n < NN && m < NN) ? g_buf[OFF_AT + (size_t)m * NN + n] : 0.f;
        }
        for (int idx = tid; idx < 64 * 16; idx += 256) {
            int c4 = idx & 15, k = idx >> 4;
            int m = k0 + k;
            float4 v = (m < NN) ? *(const float4*)&srcp[(size_t)m * 2048 + col0 + c4 * 4]
                                : make_float4(0.f, 0.f, 0.f, 0.f);
            *(float4*)&Xs[k * 64 + c4 * 4] = v;
        }
        __syncthreads();
        #pragma unroll
        for (int k = 0; k < 64; k++) {
            float a0 = As[k * 34 + tn * 2];
            float a1 = As[k * 34 + tn * 2 + 1];
            float4 x4 = *(const float4*)&Xs[k * 64 + tc * 4];
            const float* xx = (const float*)&x4;
            #pragma unroll
            for (int j = 0; j < 4; j++) {
                acc[0][j] += a0 * xx[j];
                acc[1][j] += a1 * xx[j];
            }
        }
    }
    #pragma unroll
    for (int i = 0; i < 2; i++) {
        int n = n0 + tn * 2 + i;
        if (n < NN) {
            float4 v = make_float4(acc[i][0], acc[i][1], acc[i][2], acc[i][3]);
            size_t doff = (size_t)n * 2048 + col0 + tc * 4;
            *(float4*)&dstp[doff] = v;
            if (dstp2) *(float4*)&dstp2[doff] = v;
        }
    }
}

__device__ __forceinline__ void gate_item(int s, int it, float* smem, int tid) {
    int half = (it >= 614) ? 1 : 0;
    int idx0 = it - half * 614;
    int lay = (idx0 >= NN) ? 1 : 0;
    int n = idx0 - lay * NN;
    int t = lay ? (s - 1) : s;
    if (t < 0 || t >= TT) return;
    float* xh = smem;                        // [32][128]
    float* xx = smem + 4096;                 // [32][128]
    size_t Hoff = lay ? OFF_H1 : OFF_H0;
    size_t Aoff = lay ? OFF_AGG1 : OFF_AGG0;
    __syncthreads();                         // prev item done with smem
    for (int idx = tid; idx < 4096; idx += 256) {
        int bl = idx >> 7, c = idx & 127;
        float v = (c < 64) ? g_buf[Hoff + (size_t)n * 2048 + bl * 64 + c]
                           : g_buf[Aoff + (size_t)n * 2048 + bl * 64 + (c - 64)];
        xh[idx] = v;
    }
    if (lay) {
        size_t pb = ((size_t)t * NN + n) * 2048;
        for (int idx = tid; idx < 4096; idx += 256) {
            int bl = idx >> 7, c = idx & 127;
            float v = (c < 64) ? g_buf[OFF_OUT0 + pb + bl * 64 + c]
                               : g_buf[OFF_AX1 + pb + bl * 64 + (c - 64)];
            xx[idx] = v;
        }
    }
    __syncthreads();
    int o = tid & 63, bl0 = (tid >> 6) * 8;
    int oc = half * 64 + o;                  // W column
    size_t pbase = ((size_t)t * NN + n) * 32;
    float acc[8];
    if (lay) {
        float b0 = g_buf[BG1 + (size_t)n * 128 + oc];
        #pragma unroll
        for (int j = 0; j < 8; j++) acc[j] = b0;
    } else {
        #pragma unroll
        for (int j = 0; j < 8; j++)
            acc[j] = g_buf[OFF_GXP + (pbase + bl0 + j) * 128 + oc];
    }

#define GATE_MAC(WP, XP)                                                       \
    _Pragma("unroll 2")                                                        \
    for (int kq = 0; kq < 128; kq += 4) {                                      \
        float w0 = (WP)[(kq + 0) * 128 + oc];                                  \
        float w1 = (WP)[(kq + 1) * 128 + oc];                                  \
        float w2 = (WP)[(kq + 2) * 128 + oc];                                  \
        float w3 = (WP)[(kq + 3) * 128 + oc];                                  \
        _Pragma("unroll")                                                      \
        for (int j = 0; j < 8; j++) {                                          \
            float4 xv = *(const float4*)&(XP)[(bl0 + j) * 128 + kq];           \
            acc[j] += xv.x * w0 + xv.y * w1 + xv.z * w2 + xv.w * w3;           \
        }                                                                      \
    }

    if (lay) {
        const float* __restrict__ W0 = g_buf + G1X + (size_t)n * 16384;
        GATE_MAC(W0, xx);
        if (t > 0) {
            const float* __restrict__ W1 = g_buf + G1H + (size_t)n * 16384;
            GATE_MAC(W1, xh);
        }
    } else if (t > 0) {
        const float* __restrict__ W0 = g_buf + G0H + (size_t)n * 16384;
        GATE_MAC(W0, xh);
    }
#undef GATE_MAC

    if (half == 0) {
        size_t ZHoff = lay ? OFF_ZH1 : OFF_ZH0;
        #pragma unroll
        for (int j = 0; j < 8; j++) {
            int b = bl0 + j;
            float zz = 1.f / (1.f + expf(-acc[j]));
            float hv = (t == 0) ? 0.f : xh[b * 128 + o];
            g_buf[ZHoff + (size_t)n * 2048 + (size_t)b * 64 + o] = zz * hv;
        }
    } else {
        size_t Roff = lay ? OFF_R1 : OFF_R0;
        #pragma unroll
        for (int j = 0; j < 8; j++) {
            int b = bl0 + j;
            float r = 1.f / (1.f + expf(-acc[j]));
            g_buf[Roff + (size_t)n * 2048 + (size_t)b * 64 + o] = r;
        }
    }
}

__device__ __forceinline__ void upd_item(int s, int it, float* smem, int tid) {
    int half = (it >= 614) ? 1 : 0;
    int idx0 = it - half * 614;
    int lay = (idx0 >= NN) ? 1 : 0;
    int n = idx0 - lay * NN;
    int t = lay ? (s - 1) : s;
    if (t < 0 || t >= TT) return;
    float* xh = smem;                        // [16][128]
    float* xx = smem + 2048;                 // [16][128]
    size_t ZHoff = lay ? OFF_ZH1 : OFF_ZH0;
    size_t Aoff  = lay ? OFF_AGG1 : OFF_AGG0;
    __syncthreads();
    for (int idx = tid; idx < 2048; idx += 256) {
        int bl = idx >> 7, c = idx & 127;
        int bg = half * 16 + bl;
        float v = (c < 64) ? g_buf[ZHoff + (size_t)n * 2048 + bg * 64 + c]
                           : g_buf[Aoff + (size_t)n * 2048 + bg * 64 + (c - 64)];
        xh[idx] = v;
    }
    if (lay) {
        size_t pb = ((size_t)t * NN + n) * 2048;
        for (int idx = tid; idx < 2048; idx += 256) {
            int bl = idx >> 7, c = idx & 127;
            int bg = half * 16 + bl;
            float v = (c < 64) ? g_buf[OFF_OUT0 + pb + bg * 64 + c]
                               : g_buf[OFF_AX1 + pb + bg * 64 + (c - 64)];
            xx[idx] = v;
        }
    }
    __syncthreads();
    int o = tid & 63, bl0 = (tid >> 6) * 4;
    size_t pbase = ((size_t)t * NN + n) * 32;
    float acc[4];
    if (lay) {
        float b0 = g_buf[BU1 + (size_t)n * 64 + o];
        #pragma unroll
        for (int j = 0; j < 4; j++) acc[j] = b0;
    } else {
        #pragma unroll
        for (int j = 0; j < 4; j++)
            acc[j] = g_buf[OFF_UXP + (pbase + half * 16 + bl0 + j) * 64 + o];
    }

#define UPD_MAC(WP, XP)                                                        \
    _Pragma("unroll 2")                                                        \
    for (int kq = 0; kq < 128; kq += 4) {                                      \
        float w0 = (WP)[(kq + 0) * 64 + o];                                    \
        float w1 = (WP)[(kq + 1) * 64 + o];                                    \
        float w2 = (WP)[(kq + 2) * 64 + o];                                    \
        float w3 = (WP)[(kq + 3) * 64 + o];                                    \
        _Pragma("unroll")                                                      \
        for (int j = 0; j < 4; j++) {                                          \
            float4 xv = *(const float4*)&(XP)[(bl0 + j) * 128 + kq];           \
            acc[j] += xv.x * w0 + xv.y * w1 + xv.z * w2 + xv.w * w3;           \
        }                                                                      \
    }

    if (lay) {
        const float* __restrict__ W0 = g_buf + U1X + (size_t)n * 8192;
        UPD_MAC(W0, xx);
        if (t > 0) {
            const float* __restrict__ W1 = g_buf + U1H + (size_t)n * 8192;
            UPD_MAC(W1, xh);
        }
    } else if (t > 0) {
        const float* __restrict__ W0 = g_buf + U0H + (size_t)n * 8192;
        UPD_MAC(W0, xh);
    }
#undef UPD_MAC

    size_t Hoff = lay ? OFF_H1 : OFF_H0;
    size_t Roff = lay ? OFF_R1 : OFF_R0;
    #pragma unroll
    for (int j = 0; j < 4; j++) {
        int bg = half * 16 + bl0 + j;
        size_t base = (size_t)n * 2048 + (size_t)bg * 64 + o;
        float hc = tanhf(acc[j]);
        float r = g_buf[Roff + base];
        float hold = (t == 0) ? 0.f : g_buf[Hoff + base];
        float hn = r * hold + (1.f - r) * hc;
        g_buf[Hoff + base] = hn;
        if (!lay) g_buf[OFF_OUT0 + (pbase + bg) * 64 + o] = hn;
    }
}

// grid MUST be 1024 (4 blocks/CU exactly; VGPR<=128 via launch_bounds, LDS 32KB).
__global__ __launch_bounds__(256, 4) void k_scan() {
    __shared__ float smem[8192];             // 32 KB union
    int tid = threadIdx.x;
    unsigned nB = gridDim.x;
    for (int s = 0; s <= TT; s++) {
        if (s >= 1) {
            for (unsigned it = blockIdx.x; it < 640; it += nB) agg_item(s, 0, it, smem, tid);
            grid_bar(nB);
        }
        for (unsigned it = blockIdx.x; it < 1228; it += nB) gate_item(s, it, smem, tid);
        grid_bar(nB);
        if (s >= 1) {
            for (unsigned it = blockIdx.x; it < 640; it += nB) agg_item(s, 1, it, smem, tid);
            grid_bar(nB);
        }
        for (unsigned it = blockIdx.x; it < 1228; it += nB) upd_item(s, it, smem, tid);
        grid_bar(nB);
    }
}

// ---------------- fused attention (t=T-1 only) + LN1; 4 (b,n) per block ----------------
// r13: i4-blocked projection — float4 broadcast x reads, coalesced w loads.
__global__ __launch_bounds__(256) void k_attn() {
    int wid = threadIdx.x >> 6;
    int lane = threadIdx.x & 63;
    int g = blockIdx.x * 4 + wid;
    int b = g / NN, n = g - b * NN;
    __shared__ float x[4][TT][HH], kk[4][TT][HH], vv[4][TT][HH];
    __shared__ float q[4][HH], o1[4][HH], sc[4][HEADS][TT], aw[4][HEADS][TT];
    float mw = g_buf[S_MLW + lane];
    float mb = g_buf[S_MLB + lane];
    #pragma unroll
    for (int tt = 0; tt < TT; tt++) {
        float s = g_buf[S_SRC + ((size_t)b * TT + tt) * NN + n];
        x[wid][tt][lane] = s * mw + mb + g_buf[OFF_PE + tt * HH + lane];
    }
    __syncthreads();
    float ka[TT], va[TT];
    #pragma unroll
    for (int tt = 0; tt < TT; tt++) { ka[tt] = g_buf[S_BK + lane]; va[tt] = g_buf[S_BV + lane]; }
    float qa = g_buf[S_BQ + lane];
    for (int i0 = 0; i0 < HH; i0 += 4) {
        float wk0 = g_buf[S_WK + (i0 + 0) * HH + lane];
        float wk1 = g_buf[S_WK + (i0 + 1) * HH + lane];
        float wk2 = g_buf[S_WK + (i0 + 2) * HH + lane];
        float wk3 = g_buf[S_WK + (i0 + 3) * HH + lane];
        float wv0 = g_buf[S_WV + (i0 + 0) * HH + lane];
        float wv1 = g_buf[S_WV + (i0 + 1) * HH + lane];
        float wv2 = g_buf[S_WV + (i0 + 2) * HH + lane];
        float wv3 = g_buf[S_WV + (i0 + 3) * HH + lane];
        float wq0 = g_buf[S_WQ + (i0 + 0) * HH + lane];
        float wq1 = g_buf[S_WQ + (i0 + 1) * HH + lane];
        float wq2 = g_buf[S_WQ + (i0 + 2) * HH + lane];
        float wq3 = g_buf[S_WQ + (i0 + 3) * HH + lane];
        float4 xq = *(const float4*)&x[wid][TT - 1][i0];
        qa += xq.x * wq0 + xq.y * wq1 + xq.z * wq2 + xq.w * wq3;
        #pragma unroll
        for (int tt = 0; tt < TT; tt++) {
            float4 xv4 = *(const float4*)&x[wid][tt][i0];   // broadcast b128
            ka[tt] += xv4.x * wk0 + xv4.y * wk1 + xv4.z * wk2 + xv4.w * wk3;
            va[tt] += xv4.x * wv0 + xv4.y * wv1 + xv4.z * wv2 + xv4.w * wv3;
        }
    }
    #pragma unroll
    for (int tt = 0; tt < TT; tt++) { kk[wid][tt][lane] = ka[tt]; vv[wid][tt][lane] = va[tt]; }
    q[wid][lane] = qa;
    __syncthreads();
    if (lane < HEADS * TT) {
        int head = lane / TT, ts = lane - head * TT;
        float s = 0.f;
        #pragma unroll
        for (int d = 0; d < HD; d++) s += q[wid][head * HD + d] * kk[wid][ts][head * HD + d];
        sc[wid][head][ts] = s * 0.25f;
    }
    __syncthreads();
    if (lane < HEADS * TT) {
        int head = lane / TT, ts = lane - head * TT;
        float mx = -1e30f;
        #pragma unroll
        for (int j = 0; j < TT; j++) mx = fmaxf(mx, sc[wid][head][j]);
        float sm = 0.f;
        #pragma unroll
        for (int j = 0; j < TT; j++) sm += expf(sc[wid][head][j] - mx);
        aw[wid][head][ts] = expf(sc[wid][head][ts] - mx) / sm;
    }
    __syncthreads();
    int head = lane >> 4;
    float oa = 0.f;
    #pragma unroll
    for (int tt = 0; tt < TT; tt++) oa += aw[wid][head][tt] * vv[wid][tt][lane];
    o1[wid][lane] = oa;
    __syncthreads();
    float acc = g_buf[S_BO + lane];
    for (int i0 = 0; i0 < HH; i0 += 4) {
        float w0 = g_buf[S_WO + (i0 + 0) * HH + lane];
        float w1 = g_buf[S_WO + (i0 + 1) * HH + lane];
        float w2 = g_buf[S_WO + (i0 + 2) * HH + lane];
        float w3 = g_buf[S_WO + (i0 + 3) * HH + lane];
        float4 ov = *(const float4*)&o1[wid][i0];
        acc += ov.x * w0 + ov.y * w1 + ov.z * w2 + ov.w * w3;
    }
    float res = x[wid][TT - 1][lane] + acc;
    float mean = wave_sum(res) * (1.f / 64.f);
    float dv = res - mean;
    float var = wave_sum(dv * dv) * (1.f / 64.f);
    float ln = dv * rsqrtf(var + 1e-5f) * g_buf[S_L1G + lane] + g_buf[S_L1B + lane];
    g_buf[OFF_OLN + ((size_t)b * NN + n) * HH + lane] = ln;
}

// ---------------- FFN + LN2; 8 tokens per block ----------------
// r13 rewrite: phase1 i4-blocked 4-j register tile; phase2 j-split across the
// 4 waves (w2 loaded 1x/block) + cross-wave reduction reusing hid[] LDS.
__global__ __launch_bounds__(256) void k_ffn() {
    int tok0 = blockIdx.x * 8;
    int tid = threadIdx.x;
    int lane = tid & 63, wvid = tid >> 6;
    __shared__ float ox[8][HH];
    __shared__ float hid[8][1024];
    for (int idx = tid; idx < 8 * HH; idx += 256) {
        int tk = idx >> 6, hh = idx & 63;
        ox[tk][hh] = g_buf[OFF_OLN + (size_t)(tok0 + tk) * HH + hh];
    }
    __syncthreads();
    // ---- phase 1: hid = relu(ox @ w1 + b1); thread owns 4 j (tid+256p) x 8 tk ----
    {
        float acc[4][8];
        #pragma unroll
        for (int p = 0; p < 4; p++) {
            float bj = g_buf[S_FB1 + tid + 256 * p];
            #pragma unroll
            for (int tk = 0; tk < 8; tk++) acc[p][tk] = bj;
        }
        for (int i0 = 0; i0 < HH; i0 += 4) {
            float w1r[4][4];
            #pragma unroll
            for (int qq = 0; qq < 4; qq++)
                #pragma unroll
                for (int p = 0; p < 4; p++)
                    w1r[p][qq] = g_buf[S_FW1 + (size_t)(i0 + qq) * 1024 + tid + 256 * p];
            #pragma unroll
            for (int tk = 0; tk < 8; tk++) {
                float4 xo = *(const float4*)&ox[tk][i0];    // broadcast b128
                const float* xp = (const float*)&xo;
                #pragma unroll
                for (int p = 0; p < 4; p++)
                    acc[p][tk] += xp[0] * w1r[p][0] + xp[1] * w1r[p][1]
                                + xp[2] * w1r[p][2] + xp[3] * w1r[p][3];
            }
        }
        #pragma unroll
        for (int p = 0; p < 4; p++)
            #pragma unroll
            for (int tk = 0; tk < 8; tk++)
                hid[tk][tid + 256 * p] = fmaxf(acc[p][tk], 0.f);
    }
    __syncthreads();
    // ---- phase 2: each wave covers j in [wvid*256, wvid*256+256) for ALL 8 tk ----
    float pa[8], pb[8];
    #pragma unroll
    for (int tk = 0; tk < 8; tk++) { pa[tk] = 0.f; pb[tk] = 0.f; }
    {
        int jbase = wvid * 256;
        #pragma unroll 2
        for (int j4 = 0; j4 < 256; j4 += 4) {
            int j0 = jbase + j4;
            float w0 = g_buf[S_FW2 + (size_t)(j0 + 0) * HH + lane];
            float w1 = g_buf[S_FW2 + (size_t)(j0 + 1) * HH + lane];
            float w2 = g_buf[S_FW2 + (size_t)(j0 + 2) * HH + lane];
            float w3 = g_buf[S_FW2 + (size_t)(j0 + 3) * HH + lane];
            #pragma unroll
            for (int tk = 0; tk < 8; tk++) {
                float4 h4 = *(const float4*)&hid[tk][j0];   // broadcast b128
                pa[tk] += h4.x * w0 + h4.y * w1;
                pb[tk] += h4.z * w2 + h4.w * w3;
            }
        }
    }
    __syncthreads();                       // all waves done reading hid
    {
        float* rp = &hid[0][0];            // reuse hid LDS as red[4][8][64]
        #pragma unroll
        for (int tk = 0; tk < 8; tk++)
            rp[(wvid * 8 + tk) * 64 + lane] = pa[tk] + pb[tk];
    }
    __syncthreads();
    int tk = wvid, hh = lane;
    float acc0 = g_buf[S_FB2 + hh], acc1 = acc0;
    {
        const float* rp = &hid[0][0];
        #pragma unroll
        for (int w = 0; w < 4; w++) {
            acc0 += rp[(w * 8 + tk) * 64 + hh];
            acc1 += rp[(w * 8 + tk + 4) * 64 + hh];
        }
    }
    #pragma unroll
    for (int ph = 0; ph < 2; ph++) {
        int tkk = tk + 4 * ph;
        float res = ox[tkk][hh] + (ph ? acc1 : acc0);
        float mean = wave_sum(res) * (1.f / 64.f);
        float dv = res - mean;
        float var = wave_sum(dv * dv) * (1.f / 64.f);
        float ln = dv * rsqrtf(var + 1e-5f) * g_buf[S_L2G + hh] + g_buf[S_L2B + hh];
        g_buf[OFF_O2 + (size_t)(tok0 + tkk) * HH + hh] = ln;
    }
}

// ---------------- final combine + horizon conv (layer-1 h is OFF_H1) ----------------
__global__ void k_final(void* out) {
    int n = blockIdx.x, b = blockIdx.y;
    int h = threadIdx.x;
    __shared__ float comb[HH];
    comb[h] = g_buf[OFF_H1 + ((size_t)n * 32 + b) * 64 + h] * g_buf[S_WS + n * HH + h]
            + g_buf[OFF_O2 + ((size_t)b * NN + n) * 64 + h] * g_buf[S_WT + n * HH + h];
    __syncthreads();
    if (h < HORIZON) {
        float acc = g_buf[S_CB + h];
        #pragma unroll
        for (int i = 0; i < HH; i++) acc += comb[i] * g_buf[S_CW + h * HH + i];
        size_t oi = ((size_t)b * HORIZON + h) * NN + n;
        if (g_flag) ((bf16*)out)[oi] = __float2bfloat16(acc);
        else        ((float*)out)[oi] = acc;
    }
}

extern "C" void kernel_launch(void* const* d_in, const int* in_sizes, int n_in,
                              void* d_out, int out_size, void* d_ws, size_t ws_size,
                              hipStream_t stream) {
    PtrPack pk;
    for (int i = 0; i < 32; i++) pk.p[i] = d_in[i];

    k_detect<<<1, 64, 0, stream>>>(d_in[1]);
    k_ingest<<<4133, 256, 0, stream>>>(pk);
    k_adj<<<NN, 512, 0, stream>>>();
    k_nodew_all<<<22335, 256, 0, stream>>>();
    k_pe<<<1, 768, 0, stream>>>();
    k_ax0<<<dim3(39, 12), 256, 0, stream>>>();
    k_xprep0<<<dim3(12, NN), 256, 0, stream>>>();

    // ---- scan megakernel: 13 supersteps, 50 device-scope barriers, one dispatch.
    // Grid MUST be 1024 (= 256 CU x 4 blocks/CU, guaranteed by launch_bounds+LDS).
    k_scan<<<1024, 256, 0, stream>>>();

    // ---- transformer branch ----
    k_attn<<<2456, 256, 0, stream>>>();
    k_ffn<<<1228, 256, 0, stream>>>();
    // ---- combine + conv ----
    k_final<<<dim3(NN, BB), 64, 0, stream>>>(d_out);
}

// Round 8
// 3741.292 us; speedup vs baseline: 2.6511x; 2.6511x over previous
//
#include <hip/hip_runtime.h>
#include <hip/hip_bf16.h>

typedef __hip_bfloat16 bf16;

constexpr int NN = 307, TT = 12, BB = 32, HH = 64, EE = 10, HEADS = 4, HD = 16, HORIZON = 12;

// ---------------- staged fp32 input offsets ----------------
constexpr int S_SRC = 0,       S_EMB = 117888,  S_GW0 = 120958,  S_GB0 = 287358,
              S_UW0 = 288638,  S_UB0 = 371838,  S_GW1 = 372478,  S_GB1 = 700158,
              S_UW1 = 701438,  S_UB1 = 865278,  S_MLW = 865918,  S_MLB = 865982,
              S_WQ  = 866046,  S_BQ  = 870142,  S_WK  = 870206,  S_BK  = 874302,
              S_WV  = 874366,  S_BV  = 878462,  S_WO  = 878526,  S_BO  = 882622,
              S_FW1 = 882686,  S_FB1 = 948222,  S_FW2 = 949246,  S_FB2 = 1014782,
              S_L1G = 1014846, S_L1B = 1014910, S_L2G = 1014974, S_L2B = 1015038,
              S_WS  = 1015102, S_WT  = 1034750, S_CW  = 1054398, S_CB  = 1055166;

// ---------------- fp32 work regions ----------------
constexpr size_t OFF_A    = 1055178;   // 307*307
constexpr size_t OFF_OUT0 = 1149427;   // [t][n][b][c] 12*307*2048
constexpr size_t OFF_H0   = 8694259;   // [n][b][c] 307*2048 (layer 0)
constexpr size_t OFF_ZH0  = 9322995;
constexpr size_t OFF_R0   = 9951731;
constexpr size_t OFF_AX0  = 11209203;  // [t][n][b] 12*307*32
constexpr size_t OFF_AX1  = 11327091;  // [t][n][b][c] 12*307*2048
constexpr size_t OFF_PE   = 18871923;  // 12*64
constexpr size_t OFF_OLN  = 18872691;
constexpr size_t OFF_O2   = 19501427;
constexpr size_t OFF_WB   = 20130164;  // fp32 reordered per-node GRU weights

// Reordered weight blocks (fp32; bf16 storage fails: scan amplifies to 0.19 absmax — r3)
constexpr size_t G0X = OFF_WB +        0;  // 307*2*128
constexpr size_t G0H = OFF_WB +    78592;  // 307*128*128
constexpr size_t BG0 = OFF_WB +  5108480;  // 307*128
constexpr size_t U0X = OFF_WB +  5147776;  // 307*2*64
constexpr size_t U0H = OFF_WB +  5187072;  // 307*128*64
constexpr size_t BU0 = OFF_WB +  7702016;  // 307*64
constexpr size_t G1X = OFF_WB +  7721664;  // 307*128*128
constexpr size_t G1H = OFF_WB + 12751552;  // 307*128*128
constexpr size_t BG1 = OFF_WB + 17781440;  // 307*128
constexpr size_t U1X = OFF_WB + 17820736;  // 307*128*64
constexpr size_t U1H = OFF_WB + 20335680;  // 307*128*64
constexpr size_t BU1 = OFF_WB + 22850624;  // 307*64
constexpr size_t OFF_GXP = OFF_WB + 22870272;       // [t][n][b][128] L0 preact x-part (bias folded)
constexpr size_t OFF_UXP = OFF_GXP + 15089664;      // [t][n][b][64]
constexpr size_t OFF_H1  = OFF_UXP + 7544832;       // layer-1 state buffers
constexpr size_t OFF_ZH1 = OFF_H1  + 628736;
constexpr size_t OFF_R1  = OFF_ZH1 + 628736;
constexpr size_t OFF_AGG0 = OFF_R1  + 628736;       // A@H (or A@ZH) per layer
constexpr size_t OFF_AGG1 = OFF_AGG0 + 628736;
constexpr size_t OFF_AT   = OFF_AGG1 + 628736;      // A^T (307*307), r16
constexpr size_t G_TOTAL  = OFF_AT + 94249 + 4096;

// r19->r20 post-mortem: r19 PASSED but k_scan = 9.7ms, VALUBusy 6.4% —
// barrier implementation, not semantics. Root cause: ACQ_REL agent RMW and
// full __threadfence() each emit buffer_inv (FULL per-XCD L2 invalidate) on
// gfx950's non-coherent L2s. 1024 blocks x 50 barriers fired 51200 invalidates
// AT ARRIVAL TIME, i.e. while co-resident blocks still streamed weights ->
// perpetual L2 cold (FETCH 1.79GB = weights refetched each phase) + a 1024-
// spinner poll storm on ONE cache line. r20 fixes the barrier only (phase
// bodies r19-verbatim): (1) split fences — RELEASE(wbl2, no inv) before
// arrive, ACQUIRE(inv) only after release observed (invalidates concentrated
// when nobody computes); (2) RELAXED atomics (ordering via explicit fences);
// (3) hierarchical 32x32 barrier, per-group counters 128B apart, s_sleep
// backoff -> 32x less line contention. Pre-commit: k_scan >2.5ms -> revert r17.

__device__ float g_buf[G_TOTAL];
__device__ int g_flag;   // 1 = inputs are bf16, 0 = fp32
__device__ unsigned g_grp_arr[32 * 32];  // one counter per 128B line
__device__ unsigned g_grp_gen[32 * 32];
__device__ unsigned g_glb_arr;
__device__ unsigned g_glb_gen;

// grid 1024 = 32 groups x 32 blocks. Phase bodies bitwise identical to r19.
__device__ __forceinline__ void grid_bar() {
    __syncthreads();
    if (threadIdx.x == 0) {
        __builtin_amdgcn_fence(__ATOMIC_RELEASE, "agent");   // wb L2 (no inv)
        unsigned grp = blockIdx.x >> 5;
        unsigned* ga = &g_grp_arr[grp * 32];
        unsigned* gg = &g_grp_gen[grp * 32];
        unsigned mygen = __hip_atomic_load(gg, __ATOMIC_RELAXED, __HIP_MEMORY_SCOPE_AGENT);
        unsigned prev = __hip_atomic_fetch_add(ga, 1u, __ATOMIC_RELAXED, __HIP_MEMORY_SCOPE_AGENT);
        if (prev == 31u) {
            __hip_atomic_store(ga, 0u, __ATOMIC_RELAXED, __HIP_MEMORY_SCOPE_AGENT);
            unsigned glbgen = __hip_atomic_load(&g_glb_gen, __ATOMIC_RELAXED, __HIP_MEMORY_SCOPE_AGENT);
            unsigned p2 = __hip_atomic_fetch_add(&g_glb_arr, 1u, __ATOMIC_RELAXED, __HIP_MEMORY_SCOPE_AGENT);
            if (p2 == 31u) {
                __hip_atomic_store(&g_glb_arr, 0u, __ATOMIC_RELAXED, __HIP_MEMORY_SCOPE_AGENT);
                __hip_atomic_store(&g_glb_gen, glbgen + 1u, __ATOMIC_RELAXED, __HIP_MEMORY_SCOPE_AGENT);
            } else {
                while (__hip_atomic_load(&g_glb_gen, __ATOMIC_RELAXED, __HIP_MEMORY_SCOPE_AGENT) == glbgen)
                    __builtin_amdgcn_s_sleep(16);
            }
            __hip_atomic_store(gg, mygen + 1u, __ATOMIC_RELAXED, __HIP_MEMORY_SCOPE_AGENT);
        } else {
            while (__hip_atomic_load(gg, __ATOMIC_RELAXED, __HIP_MEMORY_SCOPE_AGENT) == mygen)
                __builtin_amdgcn_s_sleep(8);
        }
        __builtin_amdgcn_fence(__ATOMIC_ACQUIRE, "agent");   // inv, post-release
    }
    __syncthreads();
}

__device__ __forceinline__ float wave_sum(float v) {
    #pragma unroll
    for (int off = 32; off > 0; off >>= 1) v += __shfl_xor(v, off, 64);
    return v;
}

// ---------------- dtype detection ----------------
__global__ void k_detect(const void* emb_raw) {
    const bf16* p = (const bf16*)emb_raw;
    int lane = threadIdx.x;
    float v = __bfloat162float(p[lane]);
    bool plaus = (v == v) && (fabsf(v) <= 1e4f) && (v == 0.f || fabsf(v) >= 1e-4f);
    float c = wave_sum(plaus ? 1.f : 0.f);
    if (lane == 0) g_flag = (c >= 52.f) ? 1 : 0;
}

// ---------------- ingest all inputs as fp32 ----------------
struct PtrPack { const void* p[32]; };
__device__ const int D_CNT[32] = {117888,3070,166400,1280,83200,640,327680,1280,163840,640,
                                  64,64,4096,64,4096,64,4096,64,4096,64,
                                  65536,1024,65536,64,64,64,64,64,19648,19648,768,12};
__device__ const int D_OFF[32] = {S_SRC,S_EMB,S_GW0,S_GB0,S_UW0,S_UB0,S_GW1,S_GB1,S_UW1,S_UB1,
                                  S_MLW,S_MLB,S_WQ,S_BQ,S_WK,S_BK,S_WV,S_BV,S_WO,S_BO,
                                  S_FW1,S_FB1,S_FW2,S_FB2,S_L1G,S_L1B,S_L2G,S_L2B,S_WS,S_WT,S_CW,S_CB};
__device__ const int D_CHK[33] = {0,461,473,1123,1128,1453,1456,2736,2741,3381,3384,3385,3386,
                                  3402,3403,3419,3420,3436,3437,3453,3454,3710,3714,3970,3971,
                                  3972,3973,3974,3975,4052,4129,4132,4133};

__global__ void k_ingest(PtrPack pk) {
    int bid = blockIdx.x;
    int s = 0;
    while (s < 31 && bid >= D_CHK[s + 1]) s++;
    int i = (bid - D_CHK[s]) * 256 + threadIdx.x;
    if (i >= D_CNT[s]) return;
    float v;
    if (g_flag) v = __bfloat162float(((const bf16*)pk.p[s])[i]);
    else        v = ((const float*)pk.p[s])[i];
    g_buf[(size_t)D_OFF[s] + i] = v;
}

// ---------------- adjacency (also writes A^T for aggB staging — r16) ----------------
__global__ void k_adj() {
    int n = blockIdx.x;
    int tid = threadIdx.x;            // 512
    __shared__ float en[EE];
    __shared__ float red[512];
    if (tid < EE) en[tid] = g_buf[S_EMB + n * EE + tid];
    __syncthreads();
    bool act = tid < NN;
    float d = 0.f;
    if (act) {
        #pragma unroll
        for (int e = 0; e < EE; e++) d += en[e] * g_buf[S_EMB + tid * EE + e];
        d = fmaxf(d, 0.f);
    }
    red[tid] = act ? d : -1e30f;
    __syncthreads();
    for (int s = 256; s > 0; s >>= 1) { if (tid < s) red[tid] = fmaxf(red[tid], red[tid + s]); __syncthreads(); }
    float mx = red[0];
    __syncthreads();
    float ex = act ? expf(d - mx) : 0.f;
    red[tid] = ex;
    __syncthreads();
    for (int s = 256; s > 0; s >>= 1) { if (tid < s) red[tid] += red[tid + s]; __syncthreads(); }
    float inv = 1.f / red[0];
    if (act) {
        float av = ex * inv;
        g_buf[OFF_A  + (size_t)n * NN + tid] = av;       // A[n][m]
        g_buf[OFF_AT + (size_t)tid * NN + n] = av;       // AT[m][n]
    }
}

// ---------------- per-node GRU weights -> fp32, reordered into Wx/Wh blocks ----------------
// r14: 4 outputs/thread, compile-time divisors per segment, float4 stores.
__global__ void k_nodew_all() {
    unsigned i4 = blockIdx.x * 256u + threadIdx.x;
    if (i4 >= 5717568u) return;
    float a0 = 0.f, a1 = 0.f, a2 = 0.f, a3 = 0.f;
    size_t dst;
    unsigned n;

    #define NW_ACCUM(SRCOFF, JCONST) do {                                  \
        const float* eb = g_buf + S_EMB + n * EE;                          \
        const float* wp = g_buf + (SRCOFF) + j;                            \
        _Pragma("unroll")                                                  \
        for (int e = 0; e < EE; e++) {                                     \
            float ev = eb[e];                                              \
            a0 += ev * wp[0]; a1 += ev * wp[1];                            \
            a2 += ev * wp[2]; a3 += ev * wp[3];                            \
            wp += (JCONST);                                                \
        }                                                                  \
    } while (0)

    if (i4 < 1277120u) {               // s0: gw0, J=16640 (J4=4160)
        unsigned rem = i4;
        n = rem / 4160u;
        unsigned j = (rem - n * 4160u) * 4u;
        unsigned o = j & 127u, kk = j >> 7;
        unsigned k = (kk >= 65u) ? 1u : 0u, i = kk - k * 65u;
        dst = (i == 0u) ? G0X + ((size_t)(n * 2u + k)) * 128u + o
                        : G0H + ((size_t)(n * 128u + k * 64u + (i - 1u))) * 128u + o;
        NW_ACCUM(S_GW0, 16640u);
    } else if (i4 < 1286944u) {        // s1: gb0, J=128 (J4=32)
        unsigned rem = i4 - 1277120u;
        n = rem >> 5;
        unsigned j = (rem & 31u) * 4u;
        dst = BG0 + (size_t)n * 128u + j;
        NW_ACCUM(S_GB0, 128u);
    } else if (i4 < 1925504u) {        // s2: uw0, J=8320 (J4=2080)
        unsigned rem = i4 - 1286944u;
        n = rem / 2080u;
        unsigned j = (rem - n * 2080u) * 4u;
        unsigned o = j & 63u, kk = j >> 6;
        unsigned k = (kk >= 65u) ? 1u : 0u, i = kk - k * 65u;
        dst = (i == 0u) ? U0X + ((size_t)(n * 2u + k)) * 64u + o
                        : U0H + ((size_t)(n * 128u + k * 64u + (i - 1u))) * 64u + o;
        NW_ACCUM(S_UW0, 8320u);
    } else if (i4 < 1930416u) {        // s3: ub0, J=64 (J4=16)
        unsigned rem = i4 - 1925504u;
        n = rem >> 4;
        unsigned j = (rem & 15u) * 4u;
        dst = BU0 + (size_t)n * 64u + j;
        NW_ACCUM(S_UB0, 64u);
    } else if (i4 < 4445360u) {        // s4: gw1, J=32768 (J4=8192)
        unsigned rem = i4 - 1930416u;
        n = rem >> 13;
        unsigned j = (rem & 8191u) * 4u;
        unsigned o = j & 127u, kk = j >> 7;
        unsigned k = kk >> 7, i = kk & 127u;
        dst = (i < 64u) ? G1X + ((size_t)(n * 128u + k * 64u + i)) * 128u + o
                        : G1H + ((size_t)(n * 128u + k * 64u + (i - 64u))) * 128u + o;
        NW_ACCUM(S_GW1, 32768u);
    } else if (i4 < 4455184u) {        // s5: gb1, J=128 (J4=32)
        unsigned rem = i4 - 4445360u;
        n = rem >> 5;
        unsigned j = (rem & 31u) * 4u;
        dst = BG1 + (size_t)n * 128u + j;
        NW_ACCUM(S_GB1, 128u);
    } else if (i4 < 5712656u) {        // s6: uw1, J=16384 (J4=4096)
        unsigned rem = i4 - 4455184u;
        n = rem >> 12;
        unsigned j = (rem & 4095u) * 4u;
        unsigned o = j & 63u, kk = j >> 6;
        unsigned k = kk >> 7, i = kk & 127u;
        dst = (i < 64u) ? U1X + ((size_t)(n * 128u + k * 64u + i)) * 64u + o
                        : U1H + ((size_t)(n * 128u + k * 64u + (i - 64u))) * 64u + o;
        NW_ACCUM(S_UW1, 16384u);
    } else {                           // s7: ub1, J=64 (J4=16)
        unsigned rem = i4 - 5712656u;
        n = rem >> 4;
        unsigned j = (rem & 15u) * 4u;
        dst = BU1 + (size_t)n * 64u + j;
        NW_ACCUM(S_UB1, 64u);
    }
    #undef NW_ACCUM
    *(float4*)&g_buf[dst] = make_float4(a0, a1, a2, a3);
}

// ---------------- positional embedding ----------------
__global__ void k_pe() {
    int tid = threadIdx.x;            // 768
    int t = tid >> 6, h = tid & 63;
    float ex = (float)(h & ~1) / 64.f;
    float ang = (float)t * powf(10000.f, -ex);
    g_buf[OFF_PE + tid] = (h & 1) ? cosf(ang) : sinf(ang);
}

// ---------------- AX0[t][n][b] = sum_m A[n,m] * src[b,t,m] ----------------
__global__ __launch_bounds__(256) void k_ax0() {
    int t = blockIdx.y;
    int n0 = blockIdx.x * 8;
    int b = threadIdx.x & 31, nl = threadIdx.x >> 5;
    __shared__ float As[8][68];
    __shared__ float xs[32][65];
    float acc = 0.f;
    for (int m0 = 0; m0 < NN; m0 += 64) {
        int jend = min(64, NN - m0);
        for (int idx = threadIdx.x; idx < 8 * 64; idx += 256) {
            int i = idx >> 6, jj = idx & 63;
            int n = n0 + i, m = m0 + jj;
            As[i][jj] = (n < NN && m < NN) ? g_buf[OFF_A + (size_t)n * NN + m] : 0.f;
        }
        for (int idx = threadIdx.x; idx < 32 * 64; idx += 256) {
            int bb = idx >> 6, jj = idx & 63;
            int m = m0 + jj;
            xs[bb][jj] = (m < NN) ? g_buf[S_SRC + ((size_t)bb * TT + t) * NN + m] : 0.f;
        }
        __syncthreads();
        for (int jj = 0; jj < jend; jj++) acc += As[nl][jj] * xs[b][jj];
        __syncthreads();
    }
    int n = n0 + nl;
    if (n < NN) g_buf[OFF_AX0 + ((size_t)t * NN + n) * 32 + b] = acc;
}

// ---------------- x-part preact precompute, layer 0 (K=2); grid (12, NN) ----------------
__global__ __launch_bounds__(256) void k_xprep0() {
    int t = blockIdx.x, n = blockIdx.y, tid = threadIdx.x;
    __shared__ float xv[32], ax[32];
    if (tid < 32) {
        xv[tid] = g_buf[S_SRC + ((size_t)tid * TT + t) * NN + n];
        ax[tid] = g_buf[OFF_AX0 + ((size_t)t * NN + n) * 32 + tid];
    }
    __syncthreads();
    size_t pbase = ((size_t)t * NN + n) * 32;
    for (int idx = tid; idx < 4096; idx += 256) {
        int b = idx >> 7, o = idx & 127;
        g_buf[OFF_GXP + (pbase + b) * 128 + o] =
            g_buf[BG0 + (size_t)n * 128 + o]
          + g_buf[G0X + ((size_t)n * 2 + 0) * 128 + o] * xv[b]
          + g_buf[G0X + ((size_t)n * 2 + 1) * 128 + o] * ax[b];
    }
    for (int idx = tid; idx < 2048; idx += 256) {
        int b = idx >> 6, o = idx & 63;
        g_buf[OFF_UXP + (pbase + b) * 64 + o] =
            g_buf[BU0 + (size_t)n * 64 + o]
          + g_buf[U0X + ((size_t)n * 2 + 0) * 64 + o] * xv[b]
          + g_buf[U0X + ((size_t)n * 2 + 1) * 64 + o] * ax[b];
    }
}

// ================= scan megakernel phases (bodies = r17 verbatim) =================

__device__ __forceinline__ void agg_item(int s, int mode, int it, float* smem, int tid) {
    int z = it / 320;
    int rr = it - z * 320;
    int by = rr / 10;
    int bx = rr - by * 10;
    size_t srcOff, dstOff;
    float* __restrict__ dstp2 = nullptr;
    if (mode == 0) {
        if (z == 0) { srcOff = OFF_H0; dstOff = OFF_AGG0;
                      dstp2 = g_buf + OFF_AX1 + (size_t)(s - 1) * 628736; }
        else        { srcOff = OFF_H1; dstOff = OFF_AGG1; }
    } else {
        srcOff = z ? OFF_ZH1 : OFF_ZH0;
        dstOff = z ? OFF_AGG1 : OFF_AGG0;
    }
    const float* __restrict__ srcp = g_buf + srcOff;
    float* __restrict__ dstp = g_buf + dstOff;
    int n0 = bx * 32;
    int col0 = by * 64;
    int tn = tid >> 4, tc = tid & 15;       // i0 = tn*2, col = tc*4
    float* As = smem;                        // [64][34]
    float* Xs = smem + 2176;                 // [64][64]
    float acc[2][4];
    #pragma unroll
    for (int i = 0; i < 2; i++)
        #pragma unroll
        for (int j = 0; j < 4; j++) acc[i][j] = 0.f;
    for (int k0 = 0; k0 < NN; k0 += 64) {
        __syncthreads();   // prev chunk / prev item done with smem
        for (int idx = tid; idx < 64 * 32; idx += 256) {
            int i = idx & 31, k = idx >> 5;
            int n = n0 + i, m = k0 + k;
            As[k * 34 + i] = (n < NN && m < NN) ? g_buf[OFF_AT + (size_t)m * NN + n] : 0.f;
        }
        for (int idx = tid; idx < 64 * 16; idx += 256) {
            int c4 = idx & 15, k = idx >> 4;
            int m = k0 + k;
            float4 v = (m < NN) ? *(const float4*)&srcp[(size_t)m * 2048 + col0 + c4 * 4]
                                : make_float4(0.f, 0.f, 0.f, 0.f);
            *(float4*)&Xs[k * 64 + c4 * 4] = v;
        }
        __syncthreads();
        #pragma unroll
        for (int k = 0; k < 64; k++) {
            float a0 = As[k * 34 + tn * 2];
            float a1 = As[k * 34 + tn * 2 + 1];
            float4 x4 = *(const float4*)&Xs[k * 64 + tc * 4];
            const float* xx = (const float*)&x4;
            #pragma unroll
            for (int j = 0; j < 4; j++) {
                acc[0][j] += a0 * xx[j];
                acc[1][j] += a1 * xx[j];
            }
        }
    }
    #pragma unroll
    for (int i = 0; i < 2; i++) {
        int n = n0 + tn * 2 + i;
        if (n < NN) {
            float4 v = make_float4(acc[i][0], acc[i][1], acc[i][2], acc[i][3]);
            size_t doff = (size_t)n * 2048 + col0 + tc * 4;
            *(float4*)&dstp[doff] = v;
            if (dstp2) *(float4*)&dstp2[doff] = v;
        }
    }
}

__device__ __forceinline__ void gate_item(int s, int it, float* smem, int tid) {
    int half = (it >= 614) ? 1 : 0;
    int idx0 = it - half * 614;
    int lay = (idx0 >= NN) ? 1 : 0;
    int n = idx0 - lay * NN;
    int t = lay ? (s - 1) : s;
    if (t < 0 || t >= TT) return;
    float* xh = smem;                        // [32][128]
    float* xx = smem + 4096;                 // [32][128]
    size_t Hoff = lay ? OFF_H1 : OFF_H0;
    size_t Aoff = lay ? OFF_AGG1 : OFF_AGG0;
    __syncthreads();                         // prev item done with smem
    for (int idx = tid; idx < 4096; idx += 256) {
        int bl = idx >> 7, c = idx & 127;
        float v = (c < 64) ? g_buf[Hoff + (size_t)n * 2048 + bl * 64 + c]
                           : g_buf[Aoff + (size_t)n * 2048 + bl * 64 + (c - 64)];
        xh[idx] = v;
    }
    if (lay) {
        size_t pb = ((size_t)t * NN + n) * 2048;
        for (int idx = tid; idx < 4096; idx += 256) {
            int bl = idx >> 7, c = idx & 127;
            float v = (c < 64) ? g_buf[OFF_OUT0 + pb + bl * 64 + c]
                               : g_buf[OFF_AX1 + pb + bl * 64 + (c - 64)];
            xx[idx] = v;
        }
    }
    __syncthreads();
    int o = tid & 63, bl0 = (tid >> 6) * 8;
    int oc = half * 64 + o;                  // W column
    size_t pbase = ((size_t)t * NN + n) * 32;
    float acc[8];
    if (lay) {
        float b0 = g_buf[BG1 + (size_t)n * 128 + oc];
        #pragma unroll
        for (int j = 0; j < 8; j++) acc[j] = b0;
    } else {
        #pragma unroll
        for (int j = 0; j < 8; j++)
            acc[j] = g_buf[OFF_GXP + (pbase + bl0 + j) * 128 + oc];
    }

#define GATE_MAC(WP, XP)                                                       \
    _Pragma("unroll 2")                                                        \
    for (int kq = 0; kq < 128; kq += 4) {                                      \
        float w0 = (WP)[(kq + 0) * 128 + oc];                                  \
        float w1 = (WP)[(kq + 1) * 128 + oc];                                  \
        float w2 = (WP)[(kq + 2) * 128 + oc];                                  \
        float w3 = (WP)[(kq + 3) * 128 + oc];                                  \
        _Pragma("unroll")                                                      \
        for (int j = 0; j < 8; j++) {                                          \
            float4 xv = *(const float4*)&(XP)[(bl0 + j) * 128 + kq];           \
            acc[j] += xv.x * w0 + xv.y * w1 + xv.z * w2 + xv.w * w3;           \
        }                                                                      \
    }

    if (lay) {
        const float* __restrict__ W0 = g_buf + G1X + (size_t)n * 16384;
        GATE_MAC(W0, xx);
        if (t > 0) {
            const float* __restrict__ W1 = g_buf + G1H + (size_t)n * 16384;
            GATE_MAC(W1, xh);
        }
    } else if (t > 0) {
        const float* __restrict__ W0 = g_buf + G0H + (size_t)n * 16384;
        GATE_MAC(W0, xh);
    }
#undef GATE_MAC

    if (half == 0) {
        size_t ZHoff = lay ? OFF_ZH1 : OFF_ZH0;
        #pragma unroll
        for (int j = 0; j < 8; j++) {
            int b = bl0 + j;
            float zz = 1.f / (1.f + expf(-acc[j]));
            float hv = (t == 0) ? 0.f : xh[b * 128 + o];
            g_buf[ZHoff + (size_t)n * 2048 + (size_t)b * 64 + o] = zz * hv;
        }
    } else {
        size_t Roff = lay ? OFF_R1 : OFF_R0;
        #pragma unroll
        for (int j = 0; j < 8; j++) {
            int b = bl0 + j;
            float r = 1.f / (1.f + expf(-acc[j]));
            g_buf[Roff + (size_t)n * 2048 + (size_t)b * 64 + o] = r;
        }
    }
}

__device__ __forceinline__ void upd_item(int s, int it, float* smem, int tid) {
    int half = (it >= 614) ? 1 : 0;
    int idx0 = it - half * 614;
    int lay = (idx0 >= NN) ? 1 : 0;
    int n = idx0 - lay * NN;
    int t = lay ? (s - 1) : s;
    if (t < 0 || t >= TT) return;
    float* xh = smem;                        // [16][128]
    float* xx = smem + 2048;                 // [16][128]
    size_t ZHoff = lay ? OFF_ZH1 : OFF_ZH0;
    size_t Aoff  = lay ? OFF_AGG1 : OFF_AGG0;
    __syncthreads();
    for (int idx = tid; idx < 2048; idx += 256) {
        int bl = idx >> 7, c = idx & 127;
        int bg = half * 16 + bl;
        float v = (c < 64) ? g_buf[ZHoff + (size_t)n * 2048 + bg * 64 + c]
                           : g_buf[Aoff + (size_t)n * 2048 + bg * 64 + (c - 64)];
        xh[idx] = v;
    }
    if (lay) {
        size_t pb = ((size_t)t * NN + n) * 2048;
        for (int idx = tid; idx < 2048; idx += 256) {
            int bl = idx >> 7, c = idx & 127;
            int bg = half * 16 + bl;
            float v = (c < 64) ? g_buf[OFF_OUT0 + pb + bg * 64 + c]
                               : g_buf[OFF_AX1 + pb + bg * 64 + (c - 64)];
            xx[idx] = v;
        }
    }
    __syncthreads();
    int o = tid & 63, bl0 = (tid >> 6) * 4;
    size_t pbase = ((size_t)t * NN + n) * 32;
    float acc[4];
    if (lay) {
        float b0 = g_buf[BU1 + (size_t)n * 64 + o];
        #pragma unroll
        for (int j = 0; j < 4; j++) acc[j] = b0;
    } else {
        #pragma unroll
        for (int j = 0; j < 4; j++)
            acc[j] = g_buf[OFF_UXP + (pbase + half * 16 + bl0 + j) * 64 + o];
    }

#define UPD_MAC(WP, XP)                                                        \
    _Pragma("unroll 2")                                                        \
    for (int kq = 0; kq < 128; kq += 4) {                                      \
        float w0 = (WP)[(kq + 0) * 64 + o];                                    \
        float w1 = (WP)[(kq + 1) * 64 + o];                                    \
        float w2 = (WP)[(kq + 2) * 64 + o];                                    \
        float w3 = (WP)[(kq + 3) * 64 + o];                                    \
        _Pragma("unroll")                                                      \
        for (int j = 0; j < 4; j++) {                                          \
            float4 xv = *(const float4*)&(XP)[(bl0 + j) * 128 + kq];           \
            acc[j] += xv.x * w0 + xv.y * w1 + xv.z * w2 + xv.w * w3;           \
        }                                                                      \
    }

    if (lay) {
        const float* __restrict__ W0 = g_buf + U1X + (size_t)n * 8192;
        UPD_MAC(W0, xx);
        if (t > 0) {
            const float* __restrict__ W1 = g_buf + U1H + (size_t)n * 8192;
            UPD_MAC(W1, xh);
        }
    } else if (t > 0) {
        const float* __restrict__ W0 = g_buf + U0H + (size_t)n * 8192;
        UPD_MAC(W0, xh);
    }
#undef UPD_MAC

    size_t Hoff = lay ? OFF_H1 : OFF_H0;
    size_t Roff = lay ? OFF_R1 : OFF_R0;
    #pragma unroll
    for (int j = 0; j < 4; j++) {
        int bg = half * 16 + bl0 + j;
        size_t base = (size_t)n * 2048 + (size_t)bg * 64 + o;
        float hc = tanhf(acc[j]);
        float r = g_buf[Roff + base];
        float hold = (t == 0) ? 0.f : g_buf[Hoff + base];
        float hn = r * hold + (1.f - r) * hc;
        g_buf[Hoff + base] = hn;
        if (!lay) g_buf[OFF_OUT0 + (pbase + bg) * 64 + o] = hn;
    }
}

// grid MUST be 1024 (4 blocks/CU exactly; VGPR<=128 via launch_bounds, LDS 32KB).
__global__ __launch_bounds__(256, 4) void k_scan() {
    __shared__ float smem[8192];             // 32 KB union
    int tid = threadIdx.x;
    unsigned nB = gridDim.x;
    for (int s = 0; s <= TT; s++) {
        if (s >= 1) {
            for (unsigned it = blockIdx.x; it < 640; it += nB) agg_item(s, 0, it, smem, tid);
            grid_bar();
        }
        for (unsigned it = blockIdx.x; it < 1228; it += nB) gate_item(s, it, smem, tid);
        grid_bar();
        if (s >= 1) {
            for (unsigned it = blockIdx.x; it < 640; it += nB) agg_item(s, 1, it, smem, tid);
            grid_bar();
        }
        for (unsigned it = blockIdx.x; it < 1228; it += nB) upd_item(s, it, smem, tid);
        grid_bar();
    }
}

// ---------------- fused attention (t=T-1 only) + LN1; 4 (b,n) per block ----------------
// r13: i4-blocked projection — float4 broadcast x reads, coalesced w loads.
__global__ __launch_bounds__(256) void k_attn() {
    int wid = threadIdx.x >> 6;
    int lane = threadIdx.x & 63;
    int g = blockIdx.x * 4 + wid;
    int b = g / NN, n = g - b * NN;
    __shared__ float x[4][TT][HH], kk[4][TT][HH], vv[4][TT][HH];
    __shared__ float q[4][HH], o1[4][HH], sc[4][HEADS][TT], aw[4][HEADS][TT];
    float mw = g_buf[S_MLW + lane];
    float mb = g_buf[S_MLB + lane];
    #pragma unroll
    for (int tt = 0; tt < TT; tt++) {
        float s = g_buf[S_SRC + ((size_t)b * TT + tt) * NN + n];
        x[wid][tt][lane] = s * mw + mb + g_buf[OFF_PE + tt * HH + lane];
    }
    __syncthreads();
    float ka[TT], va[TT];
    #pragma unroll
    for (int tt = 0; tt < TT; tt++) { ka[tt] = g_buf[S_BK + lane]; va[tt] = g_buf[S_BV + lane]; }
    float qa = g_buf[S_BQ + lane];
    for (int i0 = 0; i0 < HH; i0 += 4) {
        float wk0 = g_buf[S_WK + (i0 + 0) * HH + lane];
        float wk1 = g_buf[S_WK + (i0 + 1) * HH + lane];
        float wk2 = g_buf[S_WK + (i0 + 2) * HH + lane];
        float wk3 = g_buf[S_WK + (i0 + 3) * HH + lane];
        float wv0 = g_buf[S_WV + (i0 + 0) * HH + lane];
        float wv1 = g_buf[S_WV + (i0 + 1) * HH + lane];
        float wv2 = g_buf[S_WV + (i0 + 2) * HH + lane];
        float wv3 = g_buf[S_WV + (i0 + 3) * HH + lane];
        float wq0 = g_buf[S_WQ + (i0 + 0) * HH + lane];
        float wq1 = g_buf[S_WQ + (i0 + 1) * HH + lane];
        float wq2 = g_buf[S_WQ + (i0 + 2) * HH + lane];
        float wq3 = g_buf[S_WQ + (i0 + 3) * HH + lane];
        float4 xq = *(const float4*)&x[wid][TT - 1][i0];
        qa += xq.x * wq0 + xq.y * wq1 + xq.z * wq2 + xq.w * wq3;
        #pragma unroll
        for (int tt = 0; tt < TT; tt++) {
            float4 xv4 = *(const float4*)&x[wid][tt][i0];   // broadcast b128
            ka[tt] += xv4.x * wk0 + xv4.y * wk1 + xv4.z * wk2 + xv4.w * wk3;
            va[tt] += xv4.x * wv0 + xv4.y * wv1 + xv4.z * wv2 + xv4.w * wv3;
        }
    }
    #pragma unroll
    for (int tt = 0; tt < TT; tt++) { kk[wid][tt][lane] = ka[tt]; vv[wid][tt][lane] = va[tt]; }
    q[wid][lane] = qa;
    __syncthreads();
    if (lane < HEADS * TT) {
        int head = lane / TT, ts = lane - head * TT;
        float s = 0.f;
        #pragma unroll
        for (int d = 0; d < HD; d++) s += q[wid][head * HD + d] * kk[wid][ts][head * HD + d];
        sc[wid][head][ts] = s * 0.25f;
    }
    __syncthreads();
    if (lane < HEADS * TT) {
        int head = lane / TT, ts = lane - head * TT;
        float mx = -1e30f;
        #pragma unroll
        for (int j = 0; j < TT; j++) mx = fmaxf(mx, sc[wid][head][j]);
        float sm = 0.f;
        #pragma unroll
        for (int j = 0; j < TT; j++) sm += expf(sc[wid][head][j] - mx);
        aw[wid][head][ts] = expf(sc[wid][head][ts] - mx) / sm;
    }
    __syncthreads();
    int head = lane >> 4;
    float oa = 0.f;
    #pragma unroll
    for (int tt = 0; tt < TT; tt++) oa += aw[wid][head][tt] * vv[wid][tt][lane];
    o1[wid][lane] = oa;
    __syncthreads();
    float acc = g_buf[S_BO + lane];
    for (int i0 = 0; i0 < HH; i0 += 4) {
        float w0 = g_buf[S_WO + (i0 + 0) * HH + lane];
        float w1 = g_buf[S_WO + (i0 + 1) * HH + lane];
        float w2 = g_buf[S_WO + (i0 + 2) * HH + lane];
        float w3 = g_buf[S_WO + (i0 + 3) * HH + lane];
        float4 ov = *(const float4*)&o1[wid][i0];
        acc += ov.x * w0 + ov.y * w1 + ov.z * w2 + ov.w * w3;
    }
    float res = x[wid][TT - 1][lane] + acc;
    float mean = wave_sum(res) * (1.f / 64.f);
    float dv = res - mean;
    float var = wave_sum(dv * dv) * (1.f / 64.f);
    float ln = dv * rsqrtf(var + 1e-5f) * g_buf[S_L1G + lane] + g_buf[S_L1B + lane];
    g_buf[OFF_OLN + ((size_t)b * NN + n) * HH + lane] = ln;
}

// ---------------- FFN + LN2; 8 tokens per block ----------------
// r13 rewrite: phase1 i4-blocked 4-j register tile; phase2 j-split across the
// 4 waves (w2 loaded 1x/block) + cross-wave reduction reusing hid[] LDS.
__global__ __launch_bounds__(256) void k_ffn() {
    int tok0 = blockIdx.x * 8;
    int tid = threadIdx.x;
    int lane = tid & 63, wvid = tid >> 6;
    __shared__ float ox[8][HH];
    __shared__ float hid[8][1024];
    for (int idx = tid; idx < 8 * HH; idx += 256) {
        int tk = idx >> 6, hh = idx & 63;
        ox[tk][hh] = g_buf[OFF_OLN + (size_t)(tok0 + tk) * HH + hh];
    }
    __syncthreads();
    // ---- phase 1: hid = relu(ox @ w1 + b1); thread owns 4 j (tid+256p) x 8 tk ----
    {
        float acc[4][8];
        #pragma unroll
        for (int p = 0; p < 4; p++) {
            float bj = g_buf[S_FB1 + tid + 256 * p];
            #pragma unroll
            for (int tk = 0; tk < 8; tk++) acc[p][tk] = bj;
        }
        for (int i0 = 0; i0 < HH; i0 += 4) {
            float w1r[4][4];
            #pragma unroll
            for (int qq = 0; qq < 4; qq++)
                #pragma unroll
                for (int p = 0; p < 4; p++)
                    w1r[p][qq] = g_buf[S_FW1 + (size_t)(i0 + qq) * 1024 + tid + 256 * p];
            #pragma unroll
            for (int tk = 0; tk < 8; tk++) {
                float4 xo = *(const float4*)&ox[tk][i0];    // broadcast b128
                const float* xp = (const float*)&xo;
                #pragma unroll
                for (int p = 0; p < 4; p++)
                    acc[p][tk] += xp[0] * w1r[p][0] + xp[1] * w1r[p][1]
                                + xp[2] * w1r[p][2] + xp[3] * w1r[p][3];
            }
        }
        #pragma unroll
        for (int p = 0; p < 4; p++)
            #pragma unroll
            for (int tk = 0; tk < 8; tk++)
                hid[tk][tid + 256 * p] = fmaxf(acc[p][tk], 0.f);
    }
    __syncthreads();
    // ---- phase 2: each wave covers j in [wvid*256, wvid*256+256) for ALL 8 tk ----
    float pa[8], pb[8];
    #pragma unroll
    for (int tk = 0; tk < 8; tk++) { pa[tk] = 0.f; pb[tk] = 0.f; }
    {
        int jbase = wvid * 256;
        #pragma unroll 2
        for (int j4 = 0; j4 < 256; j4 += 4) {
            int j0 = jbase + j4;
            float w0 = g_buf[S_FW2 + (size_t)(j0 + 0) * HH + lane];
            float w1 = g_buf[S_FW2 + (size_t)(j0 + 1) * HH + lane];
            float w2 = g_buf[S_FW2 + (size_t)(j0 + 2) * HH + lane];
            float w3 = g_buf[S_FW2 + (size_t)(j0 + 3) * HH + lane];
            #pragma unroll
            for (int tk = 0; tk < 8; tk++) {
                float4 h4 = *(const float4*)&hid[tk][j0];   // broadcast b128
                pa[tk] += h4.x * w0 + h4.y * w1;
                pb[tk] += h4.z * w2 + h4.w * w3;
            }
        }
    }
    __syncthreads();                       // all waves done reading hid
    {
        float* rp = &hid[0][0];            // reuse hid LDS as red[4][8][64]
        #pragma unroll
        for (int tk = 0; tk < 8; tk++)
            rp[(wvid * 8 + tk) * 64 + lane] = pa[tk] + pb[tk];
    }
    __syncthreads();
    int tk = wvid, hh = lane;
    float acc0 = g_buf[S_FB2 + hh], acc1 = acc0;
    {
        const float* rp = &hid[0][0];
        #pragma unroll
        for (int w = 0; w < 4; w++) {
            acc0 += rp[(w * 8 + tk) * 64 + hh];
            acc1 += rp[(w * 8 + tk + 4) * 64 + hh];
        }
    }
    #pragma unroll
    for (int ph = 0; ph < 2; ph++) {
        int tkk = tk + 4 * ph;
        float res = ox[tkk][hh] + (ph ? acc1 : acc0);
        float mean = wave_sum(res) * (1.f / 64.f);
        float dv = res - mean;
        float var = wave_sum(dv * dv) * (1.f / 64.f);
        float ln = dv * rsqrtf(var + 1e-5f) * g_buf[S_L2G + hh] + g_buf[S_L2B + hh];
        g_buf[OFF_O2 + (size_t)(tok0 + tkk) * HH + hh] = ln;
    }
}

// ---------------- final combine + horizon conv (layer-1 h is OFF_H1) ----------------
__global__ void k_final(void* out) {
    int n = blockIdx.x, b = blockIdx.y;
    int h = threadIdx.x;
    __shared__ float comb[HH];
    comb[h] = g_buf[OFF_H1 + ((size_t)n * 32 + b) * 64 + h] * g_buf[S_WS + n * HH + h]
            + g_buf[OFF_O2 + ((size_t)b * NN + n) * 64 + h] * g_buf[S_WT + n * HH + h];
    __syncthreads();
    if (h < HORIZON) {
        float acc = g_buf[S_CB + h];
        #pragma unroll
        for (int i = 0; i < HH; i++) acc += comb[i] * g_buf[S_CW + h * HH + i];
        size_t oi = ((size_t)b * HORIZON + h) * NN + n;
        if (g_flag) ((bf16*)out)[oi] = __float2bfloat16(acc);
        else        ((float*)out)[oi] = acc;
    }
}

extern "C" void kernel_launch(void* const* d_in, const int* in_sizes, int n_in,
                              void* d_out, int out_size, void* d_ws, size_t ws_size,
                              hipStream_t stream) {
    PtrPack pk;
    for (int i = 0; i < 32; i++) pk.p[i] = d_in[i];

    k_detect<<<1, 64, 0, stream>>>(d_in[1]);
    k_ingest<<<4133, 256, 0, stream>>>(pk);
    k_adj<<<NN, 512, 0, stream>>>();
    k_nodew_all<<<22335, 256, 0, stream>>>();
    k_pe<<<1, 768, 0, stream>>>();
    k_ax0<<<dim3(39, 12), 256, 0, stream>>>();
    k_xprep0<<<dim3(12, NN), 256, 0, stream>>>();

    // ---- scan megakernel: 13 supersteps, 50 hierarchical device barriers ----
    // Grid MUST be 1024 (= 256 CU x 4 blocks/CU, guaranteed by launch_bounds+LDS).
    k_scan<<<1024, 256, 0, stream>>>();

    // ---- transformer branch ----
    k_attn<<<2456, 256, 0, stream>>>();
    k_ffn<<<1228, 256, 0, stream>>>();
    // ---- combine + conv ----
    k_final<<<dim3(NN, BB), 64, 0, stream>>>(d_out);
}

// Round 9
// 1773.632 us; speedup vs baseline: 5.5922x; 2.1094x over previous
//
#include <hip/hip_runtime.h>
#include <hip/hip_bf16.h>

typedef __hip_bfloat16 bf16;

constexpr int NN = 307, TT = 12, BB = 32, HH = 64, EE = 10, HEADS = 4, HD = 16, HORIZON = 12;

// ---------------- staged fp32 input offsets ----------------
constexpr int S_SRC = 0,       S_EMB = 117888,  S_GW0 = 120958,  S_GB0 = 287358,
              S_UW0 = 288638,  S_UB0 = 371838,  S_GW1 = 372478,  S_GB1 = 700158,
              S_UW1 = 701438,  S_UB1 = 865278,  S_MLW = 865918,  S_MLB = 865982,
              S_WQ  = 866046,  S_BQ  = 870142,  S_WK  = 870206,  S_BK  = 874302,
              S_WV  = 874366,  S_BV  = 878462,  S_WO  = 878526,  S_BO  = 882622,
              S_FW1 = 882686,  S_FB1 = 948222,  S_FW2 = 949246,  S_FB2 = 1014782,
              S_L1G = 1014846, S_L1B = 1014910, S_L2G = 1014974, S_L2B = 1015038,
              S_WS  = 1015102, S_WT  = 1034750, S_CW  = 1054398, S_CB  = 1055166;

// ---------------- fp32 work regions ----------------
constexpr size_t OFF_A    = 1055178;   // 307*307
constexpr size_t OFF_OUT0 = 1149427;   // [t][n][b][c] 12*307*2048
constexpr size_t OFF_H0   = 8694259;   // [n][b][c] 307*2048 (layer 0)
constexpr size_t OFF_ZH0  = 9322995;
constexpr size_t OFF_R0   = 9951731;
constexpr size_t OFF_AX0  = 11209203;  // [t][n][b] 12*307*32
constexpr size_t OFF_AX1  = 11327091;  // [t][n][b][c] 12*307*2048
constexpr size_t OFF_PE   = 18871923;  // 12*64
constexpr size_t OFF_OLN  = 18872691;
constexpr size_t OFF_O2   = 19501427;
constexpr size_t OFF_WB   = 20130164;  // fp32 reordered per-node GRU weights

// Reordered weight blocks (fp32; bf16 storage fails: scan amplifies to 0.19 absmax — r3)
constexpr size_t G0X = OFF_WB +        0;  // 307*2*128
constexpr size_t G0H = OFF_WB +    78592;  // 307*128*128
constexpr size_t BG0 = OFF_WB +  5108480;  // 307*128
constexpr size_t U0X = OFF_WB +  5147776;  // 307*2*64
constexpr size_t U0H = OFF_WB +  5187072;  // 307*128*64
constexpr size_t BU0 = OFF_WB +  7702016;  // 307*64
constexpr size_t G1X = OFF_WB +  7721664;  // 307*128*128
constexpr size_t G1H = OFF_WB + 12751552;  // 307*128*128
constexpr size_t BG1 = OFF_WB + 17781440;  // 307*128
constexpr size_t U1X = OFF_WB + 17820736;  // 307*128*64
constexpr size_t U1H = OFF_WB + 20335680;  // 307*128*64
constexpr size_t BU1 = OFF_WB + 22850624;  // 307*64
constexpr size_t OFF_GXP = OFF_WB + 22870272;       // [t][n][b][128] L0 preact x-part (bias folded)
constexpr size_t OFF_UXP = OFF_GXP + 15089664;      // [t][n][b][64]
constexpr size_t OFF_H1  = OFF_UXP + 7544832;       // layer-1 state buffers
constexpr size_t OFF_ZH1 = OFF_H1  + 628736;
constexpr size_t OFF_R1  = OFF_ZH1 + 628736;
constexpr size_t OFF_AGG0 = OFF_R1  + 628736;       // A@H per layer (mode0)
constexpr size_t OFF_AGG1 = OFF_AGG0 + 628736;
constexpr size_t OFF_AT   = OFF_AGG1 + 628736;      // A^T (307*307), r16
constexpr size_t OFF_AGG0B = OFF_AT + 94249;        // A@ZH per layer (mode1) — r21 dbuf
constexpr size_t OFF_AGG1B = OFF_AGG0B + 628736;
constexpr size_t G_TOTAL  = OFF_AGG1B + 628736 + 4096;

// r20->r21 post-mortem: megakernel hit its architectural cap — barrier-acquire
// must invalidate per-XCD L2 (correctness on non-coherent L2s), so the ~90MB
// weight set refetches from L3 every phase (FETCH 1.79GB unchanged r19->r20);
// at 4 blocks/CU the fetch is latency-bound (643 GB/s) -> k_scan floor ~2.8ms
// > the dispatch chain's ~1.5ms for the SAME fetch volume (chain gets 4.8
// blocks/CU + fetch/ramp overlap). Pre-commit executed: REVERT to r17 chain.
// Carried improvement (critical-path): gate r-half is independent of agg1
// (agg1 needs only ZH from z-half; gate-r reads H/AGG/OUT0/AX1). Same-stream
// dispatches serialize, so co-schedule them IN one dispatch:
//   agg0 -> gateZ(614) -> mix{agg1 + gateR}(1254) -> upd(1228)
// WAR hazard removed by double-buffering AGG: mode1 writes AGG0B/AGG1B (read
// by upd); mode0's AGG0/AGG1 (read by gate) never clobbered mid-read. Values
// and accumulation order bitwise unchanged. Phase bodies = r19/r20-verified
// device functions. Pre-commit: if total > 1855 (r17), ship plain r17 next.

__device__ float g_buf[G_TOTAL];
__device__ int g_flag;   // 1 = inputs are bf16, 0 = fp32

__device__ __forceinline__ float wave_sum(float v) {
    #pragma unroll
    for (int off = 32; off > 0; off >>= 1) v += __shfl_xor(v, off, 64);
    return v;
}

// ---------------- dtype detection ----------------
__global__ void k_detect(const void* emb_raw) {
    const bf16* p = (const bf16*)emb_raw;
    int lane = threadIdx.x;
    float v = __bfloat162float(p[lane]);
    bool plaus = (v == v) && (fabsf(v) <= 1e4f) && (v == 0.f || fabsf(v) >= 1e-4f);
    float c = wave_sum(plaus ? 1.f : 0.f);
    if (lane == 0) g_flag = (c >= 52.f) ? 1 : 0;
}

// ---------------- ingest all inputs as fp32 ----------------
struct PtrPack { const void* p[32]; };
__device__ const int D_CNT[32] = {117888,3070,166400,1280,83200,640,327680,1280,163840,640,
                                  64,64,4096,64,4096,64,4096,64,4096,64,
                                  65536,1024,65536,64,64,64,64,64,19648,19648,768,12};
__device__ const int D_OFF[32] = {S_SRC,S_EMB,S_GW0,S_GB0,S_UW0,S_UB0,S_GW1,S_GB1,S_UW1,S_UB1,
                                  S_MLW,S_MLB,S_WQ,S_BQ,S_WK,S_BK,S_WV,S_BV,S_WO,S_BO,
                                  S_FW1,S_FB1,S_FW2,S_FB2,S_L1G,S_L1B,S_L2G,S_L2B,S_WS,S_WT,S_CW,S_CB};
__device__ const int D_CHK[33] = {0,461,473,1123,1128,1453,1456,2736,2741,3381,3384,3385,3386,
                                  3402,3403,3419,3420,3436,3437,3453,3454,3710,3714,3970,3971,
                                  3972,3973,3974,3975,4052,4129,4132,4133};

__global__ void k_ingest(PtrPack pk) {
    int bid = blockIdx.x;
    int s = 0;
    while (s < 31 && bid >= D_CHK[s + 1]) s++;
    int i = (bid - D_CHK[s]) * 256 + threadIdx.x;
    if (i >= D_CNT[s]) return;
    float v;
    if (g_flag) v = __bfloat162float(((const bf16*)pk.p[s])[i]);
    else        v = ((const float*)pk.p[s])[i];
    g_buf[(size_t)D_OFF[s] + i] = v;
}

// ---------------- adjacency (also writes A^T for agg staging — r16) ----------------
__global__ void k_adj() {
    int n = blockIdx.x;
    int tid = threadIdx.x;            // 512
    __shared__ float en[EE];
    __shared__ float red[512];
    if (tid < EE) en[tid] = g_buf[S_EMB + n * EE + tid];
    __syncthreads();
    bool act = tid < NN;
    float d = 0.f;
    if (act) {
        #pragma unroll
        for (int e = 0; e < EE; e++) d += en[e] * g_buf[S_EMB + tid * EE + e];
        d = fmaxf(d, 0.f);
    }
    red[tid] = act ? d : -1e30f;
    __syncthreads();
    for (int s = 256; s > 0; s >>= 1) { if (tid < s) red[tid] = fmaxf(red[tid], red[tid + s]); __syncthreads(); }
    float mx = red[0];
    __syncthreads();
    float ex = act ? expf(d - mx) : 0.f;
    red[tid] = ex;
    __syncthreads();
    for (int s = 256; s > 0; s >>= 1) { if (tid < s) red[tid] += red[tid + s]; __syncthreads(); }
    float inv = 1.f / red[0];
    if (act) {
        float av = ex * inv;
        g_buf[OFF_A  + (size_t)n * NN + tid] = av;       // A[n][m]
        g_buf[OFF_AT + (size_t)tid * NN + n] = av;       // AT[m][n]
    }
}

// ---------------- per-node GRU weights -> fp32, reordered into Wx/Wh blocks ----------------
// r14: 4 outputs/thread, compile-time divisors per segment, float4 stores.
__global__ void k_nodew_all() {
    unsigned i4 = blockIdx.x * 256u + threadIdx.x;
    if (i4 >= 5717568u) return;
    float a0 = 0.f, a1 = 0.f, a2 = 0.f, a3 = 0.f;
    size_t dst;
    unsigned n;

    #define NW_ACCUM(SRCOFF, JCONST) do {                                  \
        const float* eb = g_buf + S_EMB + n * EE;                          \
        const float* wp = g_buf + (SRCOFF) + j;                            \
        _Pragma("unroll")                                                  \
        for (int e = 0; e < EE; e++) {                                     \
            float ev = eb[e];                                              \
            a0 += ev * wp[0]; a1 += ev * wp[1];                            \
            a2 += ev * wp[2]; a3 += ev * wp[3];                            \
            wp += (JCONST);                                                \
        }                                                                  \
    } while (0)

    if (i4 < 1277120u) {               // s0: gw0, J=16640 (J4=4160)
        unsigned rem = i4;
        n = rem / 4160u;
        unsigned j = (rem - n * 4160u) * 4u;
        unsigned o = j & 127u, kk = j >> 7;
        unsigned k = (kk >= 65u) ? 1u : 0u, i = kk - k * 65u;
        dst = (i == 0u) ? G0X + ((size_t)(n * 2u + k)) * 128u + o
                        : G0H + ((size_t)(n * 128u + k * 64u + (i - 1u))) * 128u + o;
        NW_ACCUM(S_GW0, 16640u);
    } else if (i4 < 1286944u) {        // s1: gb0, J=128 (J4=32)
        unsigned rem = i4 - 1277120u;
        n = rem >> 5;
        unsigned j = (rem & 31u) * 4u;
        dst = BG0 + (size_t)n * 128u + j;
        NW_ACCUM(S_GB0, 128u);
    } else if (i4 < 1925504u) {        // s2: uw0, J=8320 (J4=2080)
        unsigned rem = i4 - 1286944u;
        n = rem / 2080u;
        unsigned j = (rem - n * 2080u) * 4u;
        unsigned o = j & 63u, kk = j >> 6;
        unsigned k = (kk >= 65u) ? 1u : 0u, i = kk - k * 65u;
        dst = (i == 0u) ? U0X + ((size_t)(n * 2u + k)) * 64u + o
                        : U0H + ((size_t)(n * 128u + k * 64u + (i - 1u))) * 64u + o;
        NW_ACCUM(S_UW0, 8320u);
    } else if (i4 < 1930416u) {        // s3: ub0, J=64 (J4=16)
        unsigned rem = i4 - 1925504u;
        n = rem >> 4;
        unsigned j = (rem & 15u) * 4u;
        dst = BU0 + (size_t)n * 64u + j;
        NW_ACCUM(S_UB0, 64u);
    } else if (i4 < 4445360u) {        // s4: gw1, J=32768 (J4=8192)
        unsigned rem = i4 - 1930416u;
        n = rem >> 13;
        unsigned j = (rem & 8191u) * 4u;
        unsigned o = j & 127u, kk = j >> 7;
        unsigned k = kk >> 7, i = kk & 127u;
        dst = (i < 64u) ? G1X + ((size_t)(n * 128u + k * 64u + i)) * 128u + o
                        : G1H + ((size_t)(n * 128u + k * 64u + (i - 64u))) * 128u + o;
        NW_ACCUM(S_GW1, 32768u);
    } else if (i4 < 4455184u) {        // s5: gb1, J=128 (J4=32)
        unsigned rem = i4 - 4445360u;
        n = rem >> 5;
        unsigned j = (rem & 31u) * 4u;
        dst = BG1 + (size_t)n * 128u + j;
        NW_ACCUM(S_GB1, 128u);
    } else if (i4 < 5712656u) {        // s6: uw1, J=16384 (J4=4096)
        unsigned rem = i4 - 4455184u;
        n = rem >> 12;
        unsigned j = (rem & 4095u) * 4u;
        unsigned o = j & 63u, kk = j >> 6;
        unsigned k = kk >> 7, i = kk & 127u;
        dst = (i < 64u) ? U1X + ((size_t)(n * 128u + k * 64u + i)) * 64u + o
                        : U1H + ((size_t)(n * 128u + k * 64u + (i - 64u))) * 64u + o;
        NW_ACCUM(S_UW1, 16384u);
    } else {                           // s7: ub1, J=64 (J4=16)
        unsigned rem = i4 - 5712656u;
        n = rem >> 4;
        unsigned j = (rem & 15u) * 4u;
        dst = BU1 + (size_t)n * 64u + j;
        NW_ACCUM(S_UB1, 64u);
    }
    #undef NW_ACCUM
    *(float4*)&g_buf[dst] = make_float4(a0, a1, a2, a3);
}

// ---------------- positional embedding ----------------
__global__ void k_pe() {
    int tid = threadIdx.x;            // 768
    int t = tid >> 6, h = tid & 63;
    float ex = (float)(h & ~1) / 64.f;
    float ang = (float)t * powf(10000.f, -ex);
    g_buf[OFF_PE + tid] = (h & 1) ? cosf(ang) : sinf(ang);
}

// ---------------- AX0[t][n][b] = sum_m A[n,m] * src[b,t,m] ----------------
__global__ __launch_bounds__(256) void k_ax0() {
    int t = blockIdx.y;
    int n0 = blockIdx.x * 8;
    int b = threadIdx.x & 31, nl = threadIdx.x >> 5;
    __shared__ float As[8][68];
    __shared__ float xs[32][65];
    float acc = 0.f;
    for (int m0 = 0; m0 < NN; m0 += 64) {
        int jend = min(64, NN - m0);
        for (int idx = threadIdx.x; idx < 8 * 64; idx += 256) {
            int i = idx >> 6, jj = idx & 63;
            int n = n0 + i, m = m0 + jj;
            As[i][jj] = (n < NN && m < NN) ? g_buf[OFF_A + (size_t)n * NN + m] : 0.f;
        }
        for (int idx = threadIdx.x; idx < 32 * 64; idx += 256) {
            int bb = idx >> 6, jj = idx & 63;
            int m = m0 + jj;
            xs[bb][jj] = (m < NN) ? g_buf[S_SRC + ((size_t)bb * TT + t) * NN + m] : 0.f;
        }
        __syncthreads();
        for (int jj = 0; jj < jend; jj++) acc += As[nl][jj] * xs[b][jj];
        __syncthreads();
    }
    int n = n0 + nl;
    if (n < NN) g_buf[OFF_AX0 + ((size_t)t * NN + n) * 32 + b] = acc;
}

// ---------------- x-part preact precompute, layer 0 (K=2); grid (12, NN) ----------------
__global__ __launch_bounds__(256) void k_xprep0() {
    int t = blockIdx.x, n = blockIdx.y, tid = threadIdx.x;
    __shared__ float xv[32], ax[32];
    if (tid < 32) {
        xv[tid] = g_buf[S_SRC + ((size_t)tid * TT + t) * NN + n];
        ax[tid] = g_buf[OFF_AX0 + ((size_t)t * NN + n) * 32 + tid];
    }
    __syncthreads();
    size_t pbase = ((size_t)t * NN + n) * 32;
    for (int idx = tid; idx < 4096; idx += 256) {
        int b = idx >> 7, o = idx & 127;
        g_buf[OFF_GXP + (pbase + b) * 128 + o] =
            g_buf[BG0 + (size_t)n * 128 + o]
          + g_buf[G0X + ((size_t)n * 2 + 0) * 128 + o] * xv[b]
          + g_buf[G0X + ((size_t)n * 2 + 1) * 128 + o] * ax[b];
    }
    for (int idx = tid; idx < 2048; idx += 256) {
        int b = idx >> 6, o = idx & 63;
        g_buf[OFF_UXP + (pbase + b) * 64 + o] =
            g_buf[BU0 + (size_t)n * 64 + o]
          + g_buf[U0X + ((size_t)n * 2 + 0) * 64 + o] * xv[b]
          + g_buf[U0X + ((size_t)n * 2 + 1) * 64 + o] * ax[b];
    }
}

// ================= chain phase bodies (r19/r20-verified device functions) =================
// mode 0: z=0 H0->AGG0 (+dual AX1[s-1]); z=1 H1->AGG1
// mode 1: z=0 ZH0->AGG0B; z=1 ZH1->AGG1B   (r21: double-buffered, enables mix overlap)
__device__ __forceinline__ void agg_item(int s, int mode, int it, float* smem, int tid) {
    int z = it / 320;
    int rr = it - z * 320;
    int by = rr / 10;
    int bx = rr - by * 10;
    size_t srcOff, dstOff;
    float* __restrict__ dstp2 = nullptr;
    if (mode == 0) {
        if (z == 0) { srcOff = OFF_H0; dstOff = OFF_AGG0;
                      dstp2 = g_buf + OFF_AX1 + (size_t)(s - 1) * 628736; }
        else        { srcOff = OFF_H1; dstOff = OFF_AGG1; }
    } else {
        srcOff = z ? OFF_ZH1 : OFF_ZH0;
        dstOff = z ? OFF_AGG1B : OFF_AGG0B;
    }
    const float* __restrict__ srcp = g_buf + srcOff;
    float* __restrict__ dstp = g_buf + dstOff;
    int n0 = bx * 32;
    int col0 = by * 64;
    int tn = tid >> 4, tc = tid & 15;       // i0 = tn*2, col = tc*4
    float* As = smem;                        // [64][34]
    float* Xs = smem + 2176;                 // [64][64]
    float acc[2][4];
    #pragma unroll
    for (int i = 0; i < 2; i++)
        #pragma unroll
        for (int j = 0; j < 4; j++) acc[i][j] = 0.f;
    for (int k0 = 0; k0 < NN; k0 += 64) {
        __syncthreads();
        for (int idx = tid; idx < 64 * 32; idx += 256) {
            int i = idx & 31, k = idx >> 5;
            int n = n0 + i, m = k0 + k;
            As[k * 34 + i] = (n < NN && m < NN) ? g_buf[OFF_AT + (size_t)m * NN + n] : 0.f;
        }
        for (int idx = tid; idx < 64 * 16; idx += 256) {
            int c4 = idx & 15, k = idx >> 4;
            int m = k0 + k;
            float4 v = (m < NN) ? *(const float4*)&srcp[(size_t)m * 2048 + col0 + c4 * 4]
                                : make_float4(0.f, 0.f, 0.f, 0.f);
            *(float4*)&Xs[k * 64 + c4 * 4] = v;
        }
        __syncthreads();
        #pragma unroll
        for (int k = 0; k < 64; k++) {
            float a0 = As[k * 34 + tn * 2];
            float a1 = As[k * 34 + tn * 2 + 1];
            float4 x4 = *(const float4*)&Xs[k * 64 + tc * 4];
            const float* xx = (const float*)&x4;
            #pragma unroll
            for (int j = 0; j < 4; j++) {
                acc[0][j] += a0 * xx[j];
                acc[1][j] += a1 * xx[j];
            }
        }
    }
    #pragma unroll
    for (int i = 0; i < 2; i++) {
        int n = n0 + tn * 2 + i;
        if (n < NN) {
            float4 v = make_float4(acc[i][0], acc[i][1], acc[i][2], acc[i][3]);
            size_t doff = (size_t)n * 2048 + col0 + tc * 4;
            *(float4*)&dstp[doff] = v;
            if (dstp2) *(float4*)&dstp2[doff] = v;
        }
    }
}

__device__ __forceinline__ void gate_item(int s, int it, float* smem, int tid) {
    int half = (it >= 614) ? 1 : 0;
    int idx0 = it - half * 614;
    int lay = (idx0 >= NN) ? 1 : 0;
    int n = idx0 - lay * NN;
    int t = lay ? (s - 1) : s;
    if (t < 0 || t >= TT) return;
    float* xh = smem;                        // [32][128]
    float* xx = smem + 4096;                 // [32][128]
    size_t Hoff = lay ? OFF_H1 : OFF_H0;
    size_t Aoff = lay ? OFF_AGG1 : OFF_AGG0;
    __syncthreads();
    for (int idx = tid; idx < 4096; idx += 256) {
        int bl = idx >> 7, c = idx & 127;
        float v = (c < 64) ? g_buf[Hoff + (size_t)n * 2048 + bl * 64 + c]
                           : g_buf[Aoff + (size_t)n * 2048 + bl * 64 + (c - 64)];
        xh[idx] = v;
    }
    if (lay) {
        size_t pb = ((size_t)t * NN + n) * 2048;
        for (int idx = tid; idx < 4096; idx += 256) {
            int bl = idx >> 7, c = idx & 127;
            float v = (c < 64) ? g_buf[OFF_OUT0 + pb + bl * 64 + c]
                               : g_buf[OFF_AX1 + pb + bl * 64 + (c - 64)];
            xx[idx] = v;
        }
    }
    __syncthreads();
    int o = tid & 63, bl0 = (tid >> 6) * 8;
    int oc = half * 64 + o;                  // W column
    size_t pbase = ((size_t)t * NN + n) * 32;
    float acc[8];
    if (lay) {
        float b0 = g_buf[BG1 + (size_t)n * 128 + oc];
        #pragma unroll
        for (int j = 0; j < 8; j++) acc[j] = b0;
    } else {
        #pragma unroll
        for (int j = 0; j < 8; j++)
            acc[j] = g_buf[OFF_GXP + (pbase + bl0 + j) * 128 + oc];
    }

#define GATE_MAC(WP, XP)                                                       \
    _Pragma("unroll 2")                                                        \
    for (int kq = 0; kq < 128; kq += 4) {                                      \
        float w0 = (WP)[(kq + 0) * 128 + oc];                                  \
        float w1 = (WP)[(kq + 1) * 128 + oc];                                  \
        float w2 = (WP)[(kq + 2) * 128 + oc];                                  \
        float w3 = (WP)[(kq + 3) * 128 + oc];                                  \
        _Pragma("unroll")                                                      \
        for (int j = 0; j < 8; j++) {                                          \
            float4 xv = *(const float4*)&(XP)[(bl0 + j) * 128 + kq];           \
            acc[j] += xv.x * w0 + xv.y * w1 + xv.z * w2 + xv.w * w3;           \
        }                                                                      \
    }

    if (lay) {
        const float* __restrict__ W0 = g_buf + G1X + (size_t)n * 16384;
        GATE_MAC(W0, xx);
        if (t > 0) {
            const float* __restrict__ W1 = g_buf + G1H + (size_t)n * 16384;
            GATE_MAC(W1, xh);
        }
    } else if (t > 0) {
        const float* __restrict__ W0 = g_buf + G0H + (size_t)n * 16384;
        GATE_MAC(W0, xh);
    }
#undef GATE_MAC

    if (half == 0) {
        size_t ZHoff = lay ? OFF_ZH1 : OFF_ZH0;
        #pragma unroll
        for (int j = 0; j < 8; j++) {
            int b = bl0 + j;
            float zz = 1.f / (1.f + expf(-acc[j]));
            float hv = (t == 0) ? 0.f : xh[b * 128 + o];
            g_buf[ZHoff + (size_t)n * 2048 + (size_t)b * 64 + o] = zz * hv;
        }
    } else {
        size_t Roff = lay ? OFF_R1 : OFF_R0;
        #pragma unroll
        for (int j = 0; j < 8; j++) {
            int b = bl0 + j;
            float r = 1.f / (1.f + expf(-acc[j]));
            g_buf[Roff + (size_t)n * 2048 + (size_t)b * 64 + o] = r;
        }
    }
}

__device__ __forceinline__ void upd_item(int s, int it, float* smem, int tid) {
    int half = (it >= 614) ? 1 : 0;
    int idx0 = it - half * 614;
    int lay = (idx0 >= NN) ? 1 : 0;
    int n = idx0 - lay * NN;
    int t = lay ? (s - 1) : s;
    if (t < 0 || t >= TT) return;
    float* xh = smem;                        // [16][128]
    float* xx = smem + 2048;                 // [16][128]
    size_t ZHoff = lay ? OFF_ZH1 : OFF_ZH0;
    size_t Aoff  = lay ? OFF_AGG1B : OFF_AGG0B;   // r21: reads mode1 dbuf
    __syncthreads();
    for (int idx = tid; idx < 2048; idx += 256) {
        int bl = idx >> 7, c = idx & 127;
        int bg = half * 16 + bl;
        float v = (c < 64) ? g_buf[ZHoff + (size_t)n * 2048 + bg * 64 + c]
                           : g_buf[Aoff + (size_t)n * 2048 + bg * 64 + (c - 64)];
        xh[idx] = v;
    }
    if (lay) {
        size_t pb = ((size_t)t * NN + n) * 2048;
        for (int idx = tid; idx < 2048; idx += 256) {
            int bl = idx >> 7, c = idx & 127;
            int bg = half * 16 + bl;
            float v = (c < 64) ? g_buf[OFF_OUT0 + pb + bg * 64 + c]
                               : g_buf[OFF_AX1 + pb + bg * 64 + (c - 64)];
            xx[idx] = v;
        }
    }
    __syncthreads();
    int o = tid & 63, bl0 = (tid >> 6) * 4;
    size_t pbase = ((size_t)t * NN + n) * 32;
    float acc[4];
    if (lay) {
        float b0 = g_buf[BU1 + (size_t)n * 64 + o];
        #pragma unroll
        for (int j = 0; j < 4; j++) acc[j] = b0;
    } else {
        #pragma unroll
        for (int j = 0; j < 4; j++)
            acc[j] = g_buf[OFF_UXP + (pbase + half * 16 + bl0 + j) * 64 + o];
    }

#define UPD_MAC(WP, XP)                                                        \
    _Pragma("unroll 2")                                                        \
    for (int kq = 0; kq < 128; kq += 4) {                                      \
        float w0 = (WP)[(kq + 0) * 64 + o];                                    \
        float w1 = (WP)[(kq + 1) * 64 + o];                                    \
        float w2 = (WP)[(kq + 2) * 64 + o];                                    \
        float w3 = (WP)[(kq + 3) * 64 + o];                                    \
        _Pragma("unroll")                                                      \
        for (int j = 0; j < 4; j++) {                                          \
            float4 xv = *(const float4*)&(XP)[(bl0 + j) * 128 + kq];           \
            acc[j] += xv.x * w0 + xv.y * w1 + xv.z * w2 + xv.w * w3;           \
        }                                                                      \
    }

    if (lay) {
        const float* __restrict__ W0 = g_buf + U1X + (size_t)n * 8192;
        UPD_MAC(W0, xx);
        if (t > 0) {
            const float* __restrict__ W1 = g_buf + U1H + (size_t)n * 8192;
            UPD_MAC(W1, xh);
        }
    } else if (t > 0) {
        const float* __restrict__ W0 = g_buf + U0H + (size_t)n * 8192;
        UPD_MAC(W0, xh);
    }
#undef UPD_MAC

    size_t Hoff = lay ? OFF_H1 : OFF_H0;
    size_t Roff = lay ? OFF_R1 : OFF_R0;
    #pragma unroll
    for (int j = 0; j < 4; j++) {
        int bg = half * 16 + bl0 + j;
        size_t base = (size_t)n * 2048 + (size_t)bg * 64 + o;
        float hc = tanhf(acc[j]);
        float r = g_buf[Roff + base];
        float hold = (t == 0) ? 0.f : g_buf[Hoff + base];
        float hn = r * hold + (1.f - r) * hc;
        g_buf[Hoff + base] = hn;
        if (!lay) g_buf[OFF_OUT0 + (pbase + bg) * 64 + o] = hn;
    }
}

// ---------------- chain kernels (dispatch chain, r21 structure) ----------------
__global__ __launch_bounds__(256) void k_agg0(int s) {          // grid 640
    __shared__ float smem[6272];
    agg_item(s, 0, blockIdx.x, smem, threadIdx.x);
}
__global__ __launch_bounds__(256) void k_gateZ(int s) {         // grid 614 (z-half)
    __shared__ float smem[8192];
    gate_item(s, blockIdx.x, smem, threadIdx.x);
}
__global__ __launch_bounds__(256) void k_gateAll(int s) {       // grid 1228 (s=0 only)
    __shared__ float smem[8192];
    gate_item(s, blockIdx.x, smem, threadIdx.x);
}
__global__ __launch_bounds__(256) void k_mix(int s) {           // grid 1254: agg1 + gateR
    __shared__ float smem[8192];
    if (blockIdx.x < 640) agg_item(s, 1, blockIdx.x, smem, threadIdx.x);
    else                  gate_item(s, 614 + (blockIdx.x - 640), smem, threadIdx.x);
}
__global__ __launch_bounds__(256) void k_upd(int s) {           // grid 1228
    __shared__ float smem[4096];
    upd_item(s, blockIdx.x, smem, threadIdx.x);
}

// ---------------- fused attention (t=T-1 only) + LN1; 4 (b,n) per block ----------------
__global__ __launch_bounds__(256) void k_attn() {
    int wid = threadIdx.x >> 6;
    int lane = threadIdx.x & 63;
    int g = blockIdx.x * 4 + wid;
    int b = g / NN, n = g - b * NN;
    __shared__ float x[4][TT][HH], kk[4][TT][HH], vv[4][TT][HH];
    __shared__ float q[4][HH], o1[4][HH], sc[4][HEADS][TT], aw[4][HEADS][TT];
    float mw = g_buf[S_MLW + lane];
    float mb = g_buf[S_MLB + lane];
    #pragma unroll
    for (int tt = 0; tt < TT; tt++) {
        float s = g_buf[S_SRC + ((size_t)b * TT + tt) * NN + n];
        x[wid][tt][lane] = s * mw + mb + g_buf[OFF_PE + tt * HH + lane];
    }
    __syncthreads();
    float ka[TT], va[TT];
    #pragma unroll
    for (int tt = 0; tt < TT; tt++) { ka[tt] = g_buf[S_BK + lane]; va[tt] = g_buf[S_BV + lane]; }
    float qa = g_buf[S_BQ + lane];
    for (int i0 = 0; i0 < HH; i0 += 4) {
        float wk0 = g_buf[S_WK + (i0 + 0) * HH + lane];
        float wk1 = g_buf[S_WK + (i0 + 1) * HH + lane];
        float wk2 = g_buf[S_WK + (i0 + 2) * HH + lane];
        float wk3 = g_buf[S_WK + (i0 + 3) * HH + lane];
        float wv0 = g_buf[S_WV + (i0 + 0) * HH + lane];
        float wv1 = g_buf[S_WV + (i0 + 1) * HH + lane];
        float wv2 = g_buf[S_WV + (i0 + 2) * HH + lane];
        float wv3 = g_buf[S_WV + (i0 + 3) * HH + lane];
        float wq0 = g_buf[S_WQ + (i0 + 0) * HH + lane];
        float wq1 = g_buf[S_WQ + (i0 + 1) * HH + lane];
        float wq2 = g_buf[S_WQ + (i0 + 2) * HH + lane];
        float wq3 = g_buf[S_WQ + (i0 + 3) * HH + lane];
        float4 xq = *(const float4*)&x[wid][TT - 1][i0];
        qa += xq.x * wq0 + xq.y * wq1 + xq.z * wq2 + xq.w * wq3;
        #pragma unroll
        for (int tt = 0; tt < TT; tt++) {
            float4 xv4 = *(const float4*)&x[wid][tt][i0];   // broadcast b128
            ka[tt] += xv4.x * wk0 + xv4.y * wk1 + xv4.z * wk2 + xv4.w * wk3;
            va[tt] += xv4.x * wv0 + xv4.y * wv1 + xv4.z * wv2 + xv4.w * wv3;
        }
    }
    #pragma unroll
    for (int tt = 0; tt < TT; tt++) { kk[wid][tt][lane] = ka[tt]; vv[wid][tt][lane] = va[tt]; }
    q[wid][lane] = qa;
    __syncthreads();
    if (lane < HEADS * TT) {
        int head = lane / TT, ts = lane - head * TT;
        float s = 0.f;
        #pragma unroll
        for (int d = 0; d < HD; d++) s += q[wid][head * HD + d] * kk[wid][ts][head * HD + d];
        sc[wid][head][ts] = s * 0.25f;
    }
    __syncthreads();
    if (lane < HEADS * TT) {
        int head = lane / TT, ts = lane - head * TT;
        float mx = -1e30f;
        #pragma unroll
        for (int j = 0; j < TT; j++) mx = fmaxf(mx, sc[wid][head][j]);
        float sm = 0.f;
        #pragma unroll
        for (int j = 0; j < TT; j++) sm += expf(sc[wid][head][j] - mx);
        aw[wid][head][ts] = expf(sc[wid][head][ts] - mx) / sm;
    }
    __syncthreads();
    int head = lane >> 4;
    float oa = 0.f;
    #pragma unroll
    for (int tt = 0; tt < TT; tt++) oa += aw[wid][head][tt] * vv[wid][tt][lane];
    o1[wid][lane] = oa;
    __syncthreads();
    float acc = g_buf[S_BO + lane];
    for (int i0 = 0; i0 < HH; i0 += 4) {
        float w0 = g_buf[S_WO + (i0 + 0) * HH + lane];
        float w1 = g_buf[S_WO + (i0 + 1) * HH + lane];
        float w2 = g_buf[S_WO + (i0 + 2) * HH + lane];
        float w3 = g_buf[S_WO + (i0 + 3) * HH + lane];
        float4 ov = *(const float4*)&o1[wid][i0];
        acc += ov.x * w0 + ov.y * w1 + ov.z * w2 + ov.w * w3;
    }
    float res = x[wid][TT - 1][lane] + acc;
    float mean = wave_sum(res) * (1.f / 64.f);
    float dv = res - mean;
    float var = wave_sum(dv * dv) * (1.f / 64.f);
    float ln = dv * rsqrtf(var + 1e-5f) * g_buf[S_L1G + lane] + g_buf[S_L1B + lane];
    g_buf[OFF_OLN + ((size_t)b * NN + n) * HH + lane] = ln;
}

// ---------------- FFN + LN2; 8 tokens per block ----------------
__global__ __launch_bounds__(256) void k_ffn() {
    int tok0 = blockIdx.x * 8;
    int tid = threadIdx.x;
    int lane = tid & 63, wvid = tid >> 6;
    __shared__ float ox[8][HH];
    __shared__ float hid[8][1024];
    for (int idx = tid; idx < 8 * HH; idx += 256) {
        int tk = idx >> 6, hh = idx & 63;
        ox[tk][hh] = g_buf[OFF_OLN + (size_t)(tok0 + tk) * HH + hh];
    }
    __syncthreads();
    {
        float acc[4][8];
        #pragma unroll
        for (int p = 0; p < 4; p++) {
            float bj = g_buf[S_FB1 + tid + 256 * p];
            #pragma unroll
            for (int tk = 0; tk < 8; tk++) acc[p][tk] = bj;
        }
        for (int i0 = 0; i0 < HH; i0 += 4) {
            float w1r[4][4];
            #pragma unroll
            for (int qq = 0; qq < 4; qq++)
                #pragma unroll
                for (int p = 0; p < 4; p++)
                    w1r[p][qq] = g_buf[S_FW1 + (size_t)(i0 + qq) * 1024 + tid + 256 * p];
            #pragma unroll
            for (int tk = 0; tk < 8; tk++) {
                float4 xo = *(const float4*)&ox[tk][i0];
                const float* xp = (const float*)&xo;
                #pragma unroll
                for (int p = 0; p < 4; p++)
                    acc[p][tk] += xp[0] * w1r[p][0] + xp[1] * w1r[p][1]
                                + xp[2] * w1r[p][2] + xp[3] * w1r[p][3];
            }
        }
        #pragma unroll
        for (int p = 0; p < 4; p++)
            #pragma unroll
            for (int tk = 0; tk < 8; tk++)
                hid[tk][tid + 256 * p] = fmaxf(acc[p][tk], 0.f);
    }
    __syncthreads();
    float pa[8], pb[8];
    #pragma unroll
    for (int tk = 0; tk < 8; tk++) { pa[tk] = 0.f; pb[tk] = 0.f; }
    {
        int jbase = wvid * 256;
        #pragma unroll 2
        for (int j4 = 0; j4 < 256; j4 += 4) {
            int j0 = jbase + j4;
            float w0 = g_buf[S_FW2 + (size_t)(j0 + 0) * HH + lane];
            float w1 = g_buf[S_FW2 + (size_t)(j0 + 1) * HH + lane];
            float w2 = g_buf[S_FW2 + (size_t)(j0 + 2) * HH + lane];
            float w3 = g_buf[S_FW2 + (size_t)(j0 + 3) * HH + lane];
            #pragma unroll
            for (int tk = 0; tk < 8; tk++) {
                float4 h4 = *(const float4*)&hid[tk][j0];
                pa[tk] += h4.x * w0 + h4.y * w1;
                pb[tk] += h4.z * w2 + h4.w * w3;
            }
        }
    }
    __syncthreads();
    {
        float* rp = &hid[0][0];
        #pragma unroll
        for (int tk = 0; tk < 8; tk++)
            rp[(wvid * 8 + tk) * 64 + lane] = pa[tk] + pb[tk];
    }
    __syncthreads();
    int tk = wvid, hh = lane;
    float acc0 = g_buf[S_FB2 + hh], acc1 = acc0;
    {
        const float* rp = &hid[0][0];
        #pragma unroll
        for (int w = 0; w < 4; w++) {
            acc0 += rp[(w * 8 + tk) * 64 + hh];
            acc1 += rp[(w * 8 + tk + 4) * 64 + hh];
        }
    }
    #pragma unroll
    for (int ph = 0; ph < 2; ph++) {
        int tkk = tk + 4 * ph;
        float res = ox[tkk][hh] + (ph ? acc1 : acc0);
        float mean = wave_sum(res) * (1.f / 64.f);
        float dv = res - mean;
        float var = wave_sum(dv * dv) * (1.f / 64.f);
        float ln = dv * rsqrtf(var + 1e-5f) * g_buf[S_L2G + hh] + g_buf[S_L2B + hh];
        g_buf[OFF_O2 + (size_t)(tok0 + tkk) * HH + hh] = ln;
    }
}

// ---------------- final combine + horizon conv (layer-1 h is OFF_H1) ----------------
__global__ void k_final(void* out) {
    int n = blockIdx.x, b = blockIdx.y;
    int h = threadIdx.x;
    __shared__ float comb[HH];
    comb[h] = g_buf[OFF_H1 + ((size_t)n * 32 + b) * 64 + h] * g_buf[S_WS + n * HH + h]
            + g_buf[OFF_O2 + ((size_t)b * NN + n) * 64 + h] * g_buf[S_WT + n * HH + h];
    __syncthreads();
    if (h < HORIZON) {
        float acc = g_buf[S_CB + h];
        #pragma unroll
        for (int i = 0; i < HH; i++) acc += comb[i] * g_buf[S_CW + h * HH + i];
        size_t oi = ((size_t)b * HORIZON + h) * NN + n;
        if (g_flag) ((bf16*)out)[oi] = __float2bfloat16(acc);
        else        ((float*)out)[oi] = acc;
    }
}

extern "C" void kernel_launch(void* const* d_in, const int* in_sizes, int n_in,
                              void* d_out, int out_size, void* d_ws, size_t ws_size,
                              hipStream_t stream) {
    PtrPack pk;
    for (int i = 0; i < 32; i++) pk.p[i] = d_in[i];

    k_detect<<<1, 64, 0, stream>>>(d_in[1]);
    k_ingest<<<4133, 256, 0, stream>>>(pk);
    k_adj<<<NN, 512, 0, stream>>>();
    k_nodew_all<<<22335, 256, 0, stream>>>();
    k_pe<<<1, 768, 0, stream>>>();
    k_ax0<<<dim3(39, 12), 256, 0, stream>>>();
    k_xprep0<<<dim3(12, NN), 256, 0, stream>>>();

    // ---- supersteps (r21 structure): agg0 -> gateZ -> {agg1 || gateR} -> upd ----
    k_gateAll<<<1228, 256, 0, stream>>>(0);
    k_upd<<<1228, 256, 0, stream>>>(0);
    for (int s = 1; s <= TT; s++) {
        k_agg0 <<<640,  256, 0, stream>>>(s);   // A@H0 (dual->AX1[s-1]), A@H1
        k_gateZ<<<614,  256, 0, stream>>>(s);   // z-half only -> ZH
        k_mix  <<<1254, 256, 0, stream>>>(s);   // A@ZH -> AGG*B  ||  gate r-half -> R
        k_upd  <<<1228, 256, 0, stream>>>(s);
    }

    // ---- transformer branch ----
    k_attn<<<2456, 256, 0, stream>>>();
    k_ffn<<<1228, 256, 0, stream>>>();
    // ---- combine + conv ----
    k_final<<<dim3(NN, BB), 64, 0, stream>>>(d_out);
}

// Round 10
// 1768.368 us; speedup vs baseline: 5.6088x; 1.0030x over previous
//
#include <hip/hip_runtime.h>
#include <hip/hip_bf16.h>

typedef __hip_bfloat16 bf16;

constexpr int NN = 307, TT = 12, BB = 32, HH = 64, EE = 10, HEADS = 4, HD = 16, HORIZON = 12;

// ---------------- staged fp32 input offsets ----------------
constexpr int S_SRC = 0,       S_EMB = 117888,  S_GW0 = 120958,  S_GB0 = 287358,
              S_UW0 = 288638,  S_UB0 = 371838,  S_GW1 = 372478,  S_GB1 = 700158,
              S_UW1 = 701438,  S_UB1 = 865278,  S_MLW = 865918,  S_MLB = 865982,
              S_WQ  = 866046,  S_BQ  = 870142,  S_WK  = 870206,  S_BK  = 874302,
              S_WV  = 874366,  S_BV  = 878462,  S_WO  = 878526,  S_BO  = 882622,
              S_FW1 = 882686,  S_FB1 = 948222,  S_FW2 = 949246,  S_FB2 = 1014782,
              S_L1G = 1014846, S_L1B = 1014910, S_L2G = 1014974, S_L2B = 1015038,
              S_WS  = 1015102, S_WT  = 1034750, S_CW  = 1054398, S_CB  = 1055166;

// ---------------- fp32 work regions ----------------
constexpr size_t OFF_A    = 1055178;   // 307*307
constexpr size_t OFF_OUT0 = 1149427;   // [t][n][b][c] 12*307*2048
constexpr size_t OFF_H0   = 8694259;   // [n][b][c] 307*2048 (layer 0)
constexpr size_t OFF_ZH0  = 9322995;
constexpr size_t OFF_R0   = 9951731;
constexpr size_t OFF_AX0  = 11209203;  // [t][n][b] 12*307*32
constexpr size_t OFF_AX1  = 11327091;  // [t][n][b][c] 12*307*2048
constexpr size_t OFF_PE   = 18871923;  // 12*64
constexpr size_t OFF_OLN  = 18872691;
constexpr size_t OFF_O2   = 19501427;
constexpr size_t OFF_WB   = 20130164;  // fp32 reordered per-node GRU weights

// Reordered weight blocks (fp32; bf16 storage fails: scan amplifies to 0.19 absmax — r3)
constexpr size_t G0X = OFF_WB +        0;  // 307*2*128
constexpr size_t G0H = OFF_WB +    78592;  // 307*128*128
constexpr size_t BG0 = OFF_WB +  5108480;  // 307*128
constexpr size_t U0X = OFF_WB +  5147776;  // 307*2*64
constexpr size_t U0H = OFF_WB +  5187072;  // 307*128*64
constexpr size_t BU0 = OFF_WB +  7702016;  // 307*64
constexpr size_t G1X = OFF_WB +  7721664;  // 307*128*128
constexpr size_t G1H = OFF_WB + 12751552;  // 307*128*128
constexpr size_t BG1 = OFF_WB + 17781440;  // 307*128
constexpr size_t U1X = OFF_WB + 17820736;  // 307*128*64
constexpr size_t U1H = OFF_WB + 20335680;  // 307*128*64
constexpr size_t BU1 = OFF_WB + 22850624;  // 307*64
constexpr size_t OFF_GXP = OFF_WB + 22870272;       // [t][n][b][128] L0 preact x-part (bias folded)
constexpr size_t OFF_UXP = OFF_GXP + 15089664;      // [t][n][b][64]
constexpr size_t OFF_H1  = OFF_UXP + 7544832;       // layer-1 state buffers
constexpr size_t OFF_ZH1 = OFF_H1  + 628736;
constexpr size_t OFF_R1  = OFF_ZH1 + 628736;
constexpr size_t OFF_AGG0 = OFF_R1  + 628736;       // A@H per layer (mode0)
constexpr size_t OFF_AGG1 = OFF_AGG0 + 628736;
constexpr size_t OFF_AT   = OFF_AGG1 + 628736;      // A^T (307*307), r16
constexpr size_t OFF_AGG0B = OFF_AT + 94249;        // A@ZH per layer (mode1) — r21 dbuf
constexpr size_t OFF_AGG1B = OFF_AGG0B + 628736;
constexpr size_t G_TOTAL  = OFF_AGG1B + 628736 + 4096;

// r21->r22: r21 matched prediction (1774us, best). Two remaining structural
// inefficiencies: (a) gateZ at 614 blocks = 2.4/CU (latency-starved regime;
// r17's updM batch-split proved the W-traffic doubling is harmless — TLP, not
// L3 BW, binds). Gate items now split by BATCH half too: item space 2456 =
// oh(z/r) x bh x lay x n; gateZ grid 1228, mix 640+1228=1868. Per-element
// accumulation chains bitwise unchanged (init + kq-ascending MAC identical).
// (b) transformer branch (attn 60 + ffn 73us) is serial tail but chain-
// independent (disjoint buffers: src/PE/W->OLN->O2). Folded via the k_mix
// trick: attn blocks appended to agg0(s=1) (grid 3096, union smem 40.4KB ->
// 3 blocks/CU for that dispatch only), ffn appended to agg0(s=2) (grid 1868).
// VALU-heavy attn/ffn blocks fill the latency stalls of agg blocks. k_final
// (needs H1+O2) stays last. Pre-commit: regression vs 1774 -> revert r21.

__device__ float g_buf[G_TOTAL];
__device__ int g_flag;   // 1 = inputs are bf16, 0 = fp32

__device__ __forceinline__ float wave_sum(float v) {
    #pragma unroll
    for (int off = 32; off > 0; off >>= 1) v += __shfl_xor(v, off, 64);
    return v;
}

// ---------------- dtype detection ----------------
__global__ void k_detect(const void* emb_raw) {
    const bf16* p = (const bf16*)emb_raw;
    int lane = threadIdx.x;
    float v = __bfloat162float(p[lane]);
    bool plaus = (v == v) && (fabsf(v) <= 1e4f) && (v == 0.f || fabsf(v) >= 1e-4f);
    float c = wave_sum(plaus ? 1.f : 0.f);
    if (lane == 0) g_flag = (c >= 52.f) ? 1 : 0;
}

// ---------------- ingest all inputs as fp32 ----------------
struct PtrPack { const void* p[32]; };
__device__ const int D_CNT[32] = {117888,3070,166400,1280,83200,640,327680,1280,163840,640,
                                  64,64,4096,64,4096,64,4096,64,4096,64,
                                  65536,1024,65536,64,64,64,64,64,19648,19648,768,12};
__device__ const int D_OFF[32] = {S_SRC,S_EMB,S_GW0,S_GB0,S_UW0,S_UB0,S_GW1,S_GB1,S_UW1,S_UB1,
                                  S_MLW,S_MLB,S_WQ,S_BQ,S_WK,S_BK,S_WV,S_BV,S_WO,S_BO,
                                  S_FW1,S_FB1,S_FW2,S_FB2,S_L1G,S_L1B,S_L2G,S_L2B,S_WS,S_WT,S_CW,S_CB};
__device__ const int D_CHK[33] = {0,461,473,1123,1128,1453,1456,2736,2741,3381,3384,3385,3386,
                                  3402,3403,3419,3420,3436,3437,3453,3454,3710,3714,3970,3971,
                                  3972,3973,3974,3975,4052,4129,4132,4133};

__global__ void k_ingest(PtrPack pk) {
    int bid = blockIdx.x;
    int s = 0;
    while (s < 31 && bid >= D_CHK[s + 1]) s++;
    int i = (bid - D_CHK[s]) * 256 + threadIdx.x;
    if (i >= D_CNT[s]) return;
    float v;
    if (g_flag) v = __bfloat162float(((const bf16*)pk.p[s])[i]);
    else        v = ((const float*)pk.p[s])[i];
    g_buf[(size_t)D_OFF[s] + i] = v;
}

// ---------------- adjacency (also writes A^T for agg staging — r16) ----------------
__global__ void k_adj() {
    int n = blockIdx.x;
    int tid = threadIdx.x;            // 512
    __shared__ float en[EE];
    __shared__ float red[512];
    if (tid < EE) en[tid] = g_buf[S_EMB + n * EE + tid];
    __syncthreads();
    bool act = tid < NN;
    float d = 0.f;
    if (act) {
        #pragma unroll
        for (int e = 0; e < EE; e++) d += en[e] * g_buf[S_EMB + tid * EE + e];
        d = fmaxf(d, 0.f);
    }
    red[tid] = act ? d : -1e30f;
    __syncthreads();
    for (int s = 256; s > 0; s >>= 1) { if (tid < s) red[tid] = fmaxf(red[tid], red[tid + s]); __syncthreads(); }
    float mx = red[0];
    __syncthreads();
    float ex = act ? expf(d - mx) : 0.f;
    red[tid] = ex;
    __syncthreads();
    for (int s = 256; s > 0; s >>= 1) { if (tid < s) red[tid] += red[tid + s]; __syncthreads(); }
    float inv = 1.f / red[0];
    if (act) {
        float av = ex * inv;
        g_buf[OFF_A  + (size_t)n * NN + tid] = av;       // A[n][m]
        g_buf[OFF_AT + (size_t)tid * NN + n] = av;       // AT[m][n]
    }
}

// ---------------- per-node GRU weights -> fp32, reordered into Wx/Wh blocks ----------------
__global__ void k_nodew_all() {
    unsigned i4 = blockIdx.x * 256u + threadIdx.x;
    if (i4 >= 5717568u) return;
    float a0 = 0.f, a1 = 0.f, a2 = 0.f, a3 = 0.f;
    size_t dst;
    unsigned n;

    #define NW_ACCUM(SRCOFF, JCONST) do {                                  \
        const float* eb = g_buf + S_EMB + n * EE;                          \
        const float* wp = g_buf + (SRCOFF) + j;                            \
        _Pragma("unroll")                                                  \
        for (int e = 0; e < EE; e++) {                                     \
            float ev = eb[e];                                              \
            a0 += ev * wp[0]; a1 += ev * wp[1];                            \
            a2 += ev * wp[2]; a3 += ev * wp[3];                            \
            wp += (JCONST);                                                \
        }                                                                  \
    } while (0)

    if (i4 < 1277120u) {               // s0: gw0, J=16640 (J4=4160)
        unsigned rem = i4;
        n = rem / 4160u;
        unsigned j = (rem - n * 4160u) * 4u;
        unsigned o = j & 127u, kk = j >> 7;
        unsigned k = (kk >= 65u) ? 1u : 0u, i = kk - k * 65u;
        dst = (i == 0u) ? G0X + ((size_t)(n * 2u + k)) * 128u + o
                        : G0H + ((size_t)(n * 128u + k * 64u + (i - 1u))) * 128u + o;
        NW_ACCUM(S_GW0, 16640u);
    } else if (i4 < 1286944u) {        // s1: gb0, J=128 (J4=32)
        unsigned rem = i4 - 1277120u;
        n = rem >> 5;
        unsigned j = (rem & 31u) * 4u;
        dst = BG0 + (size_t)n * 128u + j;
        NW_ACCUM(S_GB0, 128u);
    } else if (i4 < 1925504u) {        // s2: uw0, J=8320 (J4=2080)
        unsigned rem = i4 - 1286944u;
        n = rem / 2080u;
        unsigned j = (rem - n * 2080u) * 4u;
        unsigned o = j & 63u, kk = j >> 6;
        unsigned k = (kk >= 65u) ? 1u : 0u, i = kk - k * 65u;
        dst = (i == 0u) ? U0X + ((size_t)(n * 2u + k)) * 64u + o
                        : U0H + ((size_t)(n * 128u + k * 64u + (i - 1u))) * 64u + o;
        NW_ACCUM(S_UW0, 8320u);
    } else if (i4 < 1930416u) {        // s3: ub0, J=64 (J4=16)
        unsigned rem = i4 - 1925504u;
        n = rem >> 4;
        unsigned j = (rem & 15u) * 4u;
        dst = BU0 + (size_t)n * 64u + j;
        NW_ACCUM(S_UB0, 64u);
    } else if (i4 < 4445360u) {        // s4: gw1, J=32768 (J4=8192)
        unsigned rem = i4 - 1930416u;
        n = rem >> 13;
        unsigned j = (rem & 8191u) * 4u;
        unsigned o = j & 127u, kk = j >> 7;
        unsigned k = kk >> 7, i = kk & 127u;
        dst = (i < 64u) ? G1X + ((size_t)(n * 128u + k * 64u + i)) * 128u + o
                        : G1H + ((size_t)(n * 128u + k * 64u + (i - 64u))) * 128u + o;
        NW_ACCUM(S_GW1, 32768u);
    } else if (i4 < 4455184u) {        // s5: gb1, J=128 (J4=32)
        unsigned rem = i4 - 4445360u;
        n = rem >> 5;
        unsigned j = (rem & 31u) * 4u;
        dst = BG1 + (size_t)n * 128u + j;
        NW_ACCUM(S_GB1, 128u);
    } else if (i4 < 5712656u) {        // s6: uw1, J=16384 (J4=4096)
        unsigned rem = i4 - 4455184u;
        n = rem >> 12;
        unsigned j = (rem & 4095u) * 4u;
        unsigned o = j & 63u, kk = j >> 6;
        unsigned k = kk >> 7, i = kk & 127u;
        dst = (i < 64u) ? U1X + ((size_t)(n * 128u + k * 64u + i)) * 64u + o
                        : U1H + ((size_t)(n * 128u + k * 64u + (i - 64u))) * 64u + o;
        NW_ACCUM(S_UW1, 16384u);
    } else {                           // s7: ub1, J=64 (J4=16)
        unsigned rem = i4 - 5712656u;
        n = rem >> 4;
        unsigned j = (rem & 15u) * 4u;
        dst = BU1 + (size_t)n * 64u + j;
        NW_ACCUM(S_UB1, 64u);
    }
    #undef NW_ACCUM
    *(float4*)&g_buf[dst] = make_float4(a0, a1, a2, a3);
}

// ---------------- positional embedding ----------------
__global__ void k_pe() {
    int tid = threadIdx.x;            // 768
    int t = tid >> 6, h = tid & 63;
    float ex = (float)(h & ~1) / 64.f;
    float ang = (float)t * powf(10000.f, -ex);
    g_buf[OFF_PE + tid] = (h & 1) ? cosf(ang) : sinf(ang);
}

// ---------------- AX0[t][n][b] = sum_m A[n,m] * src[b,t,m] ----------------
__global__ __launch_bounds__(256) void k_ax0() {
    int t = blockIdx.y;
    int n0 = blockIdx.x * 8;
    int b = threadIdx.x & 31, nl = threadIdx.x >> 5;
    __shared__ float As[8][68];
    __shared__ float xs[32][65];
    float acc = 0.f;
    for (int m0 = 0; m0 < NN; m0 += 64) {
        int jend = min(64, NN - m0);
        for (int idx = threadIdx.x; idx < 8 * 64; idx += 256) {
            int i = idx >> 6, jj = idx & 63;
            int n = n0 + i, m = m0 + jj;
            As[i][jj] = (n < NN && m < NN) ? g_buf[OFF_A + (size_t)n * NN + m] : 0.f;
        }
        for (int idx = threadIdx.x; idx < 32 * 64; idx += 256) {
            int bb = idx >> 6, jj = idx & 63;
            int m = m0 + jj;
            xs[bb][jj] = (m < NN) ? g_buf[S_SRC + ((size_t)bb * TT + t) * NN + m] : 0.f;
        }
        __syncthreads();
        for (int jj = 0; jj < jend; jj++) acc += As[nl][jj] * xs[b][jj];
        __syncthreads();
    }
    int n = n0 + nl;
    if (n < NN) g_buf[OFF_AX0 + ((size_t)t * NN + n) * 32 + b] = acc;
}

// ---------------- x-part preact precompute, layer 0 (K=2); grid (12, NN) ----------------
__global__ __launch_bounds__(256) void k_xprep0() {
    int t = blockIdx.x, n = blockIdx.y, tid = threadIdx.x;
    __shared__ float xv[32], ax[32];
    if (tid < 32) {
        xv[tid] = g_buf[S_SRC + ((size_t)tid * TT + t) * NN + n];
        ax[tid] = g_buf[OFF_AX0 + ((size_t)t * NN + n) * 32 + tid];
    }
    __syncthreads();
    size_t pbase = ((size_t)t * NN + n) * 32;
    for (int idx = tid; idx < 4096; idx += 256) {
        int b = idx >> 7, o = idx & 127;
        g_buf[OFF_GXP + (pbase + b) * 128 + o] =
            g_buf[BG0 + (size_t)n * 128 + o]
          + g_buf[G0X + ((size_t)n * 2 + 0) * 128 + o] * xv[b]
          + g_buf[G0X + ((size_t)n * 2 + 1) * 128 + o] * ax[b];
    }
    for (int idx = tid; idx < 2048; idx += 256) {
        int b = idx >> 6, o = idx & 63;
        g_buf[OFF_UXP + (pbase + b) * 64 + o] =
            g_buf[BU0 + (size_t)n * 64 + o]
          + g_buf[U0X + ((size_t)n * 2 + 0) * 64 + o] * xv[b]
          + g_buf[U0X + ((size_t)n * 2 + 1) * 64 + o] * ax[b];
    }
}

// ================= chain phase bodies =================
// agg mode 0: z=0 H0->AGG0 (+dual AX1[s-1]); z=1 H1->AGG1
// agg mode 1: z=0 ZH0->AGG0B; z=1 ZH1->AGG1B (r21 dbuf; read by upd)
__device__ __forceinline__ void agg_item(int s, int mode, int it, float* smem, int tid) {
    int z = it / 320;
    int rr = it - z * 320;
    int by = rr / 10;
    int bx = rr - by * 10;
    size_t srcOff, dstOff;
    float* __restrict__ dstp2 = nullptr;
    if (mode == 0) {
        if (z == 0) { srcOff = OFF_H0; dstOff = OFF_AGG0;
                      dstp2 = g_buf + OFF_AX1 + (size_t)(s - 1) * 628736; }
        else        { srcOff = OFF_H1; dstOff = OFF_AGG1; }
    } else {
        srcOff = z ? OFF_ZH1 : OFF_ZH0;
        dstOff = z ? OFF_AGG1B : OFF_AGG0B;
    }
    const float* __restrict__ srcp = g_buf + srcOff;
    float* __restrict__ dstp = g_buf + dstOff;
    int n0 = bx * 32;
    int col0 = by * 64;
    int tn = tid >> 4, tc = tid & 15;       // i0 = tn*2, col = tc*4
    float* As = smem;                        // [64][34]
    float* Xs = smem + 2176;                 // [64][64]
    float acc[2][4];
    #pragma unroll
    for (int i = 0; i < 2; i++)
        #pragma unroll
        for (int j = 0; j < 4; j++) acc[i][j] = 0.f;
    for (int k0 = 0; k0 < NN; k0 += 64) {
        __syncthreads();
        for (int idx = tid; idx < 64 * 32; idx += 256) {
            int i = idx & 31, k = idx >> 5;
            int n = n0 + i, m = k0 + k;
            As[k * 34 + i] = (n < NN && m < NN) ? g_buf[OFF_AT + (size_t)m * NN + n] : 0.f;
        }
        for (int idx = tid; idx < 64 * 16; idx += 256) {
            int c4 = idx & 15, k = idx >> 4;
            int m = k0 + k;
            float4 v = (m < NN) ? *(const float4*)&srcp[(size_t)m * 2048 + col0 + c4 * 4]
                                : make_float4(0.f, 0.f, 0.f, 0.f);
            *(float4*)&Xs[k * 64 + c4 * 4] = v;
        }
        __syncthreads();
        #pragma unroll
        for (int k = 0; k < 64; k++) {
            float a0 = As[k * 34 + tn * 2];
            float a1 = As[k * 34 + tn * 2 + 1];
            float4 x4 = *(const float4*)&Xs[k * 64 + tc * 4];
            const float* xx = (const float*)&x4;
            #pragma unroll
            for (int j = 0; j < 4; j++) {
                acc[0][j] += a0 * xx[j];
                acc[1][j] += a1 * xx[j];
            }
        }
    }
    #pragma unroll
    for (int i = 0; i < 2; i++) {
        int n = n0 + tn * 2 + i;
        if (n < NN) {
            float4 v = make_float4(acc[i][0], acc[i][1], acc[i][2], acc[i][3]);
            size_t doff = (size_t)n * 2048 + col0 + tc * 4;
            *(float4*)&dstp[doff] = v;
            if (dstp2) *(float4*)&dstp2[doff] = v;
        }
    }
}

// r22 gate: item space 2456 = oh(z/r)*1228 + bh*614 + lay*307 + n.
// Per block: 64 outputs x 16 batch rows; W traffic x2 vs r21 (TLP > L3 BW).
__device__ __forceinline__ void gate_item2(int s, int it, float* smem, int tid) {
    int oh = it / 1228;
    int rem = it - oh * 1228;
    int bh = rem / 614;
    int idx0 = rem - bh * 614;
    int lay = (idx0 >= NN) ? 1 : 0;
    int n = idx0 - lay * NN;
    int t = lay ? (s - 1) : s;
    if (t < 0 || t >= TT) return;
    float* xh = smem;                        // [16][128]
    float* xx = smem + 2048;                 // [16][128]
    size_t Hoff = lay ? OFF_H1 : OFF_H0;
    size_t Aoff = lay ? OFF_AGG1 : OFF_AGG0;
    __syncthreads();
    for (int idx = tid; idx < 2048; idx += 256) {
        int bl = idx >> 7, c = idx & 127;
        int bg = bh * 16 + bl;
        float v = (c < 64) ? g_buf[Hoff + (size_t)n * 2048 + bg * 64 + c]
                           : g_buf[Aoff + (size_t)n * 2048 + bg * 64 + (c - 64)];
        xh[idx] = v;
    }
    if (lay) {
        size_t pb = ((size_t)t * NN + n) * 2048;
        for (int idx = tid; idx < 2048; idx += 256) {
            int bl = idx >> 7, c = idx & 127;
            int bg = bh * 16 + bl;
            float v = (c < 64) ? g_buf[OFF_OUT0 + pb + bg * 64 + c]
                               : g_buf[OFF_AX1 + pb + bg * 64 + (c - 64)];
            xx[idx] = v;
        }
    }
    __syncthreads();
    int o = tid & 63, bl0 = (tid >> 6) * 4;
    int oc = oh * 64 + o;                    // W column
    size_t pbase = ((size_t)t * NN + n) * 32;
    float acc[4];
    if (lay) {
        float b0 = g_buf[BG1 + (size_t)n * 128 + oc];
        #pragma unroll
        for (int j = 0; j < 4; j++) acc[j] = b0;
    } else {
        #pragma unroll
        for (int j = 0; j < 4; j++)
            acc[j] = g_buf[OFF_GXP + (pbase + bh * 16 + bl0 + j) * 128 + oc];
    }

#define GATE_MAC(WP, XP)                                                       \
    _Pragma("unroll 2")                                                        \
    for (int kq = 0; kq < 128; kq += 4) {                                      \
        float w0 = (WP)[(kq + 0) * 128 + oc];                                  \
        float w1 = (WP)[(kq + 1) * 128 + oc];                                  \
        float w2 = (WP)[(kq + 2) * 128 + oc];                                  \
        float w3 = (WP)[(kq + 3) * 128 + oc];                                  \
        _Pragma("unroll")                                                      \
        for (int j = 0; j < 4; j++) {                                          \
            float4 xv = *(const float4*)&(XP)[(bl0 + j) * 128 + kq];           \
            acc[j] += xv.x * w0 + xv.y * w1 + xv.z * w2 + xv.w * w3;           \
        }                                                                      \
    }

    if (lay) {
        const float* __restrict__ W0 = g_buf + G1X + (size_t)n * 16384;
        GATE_MAC(W0, xx);
        if (t > 0) {
            const float* __restrict__ W1 = g_buf + G1H + (size_t)n * 16384;
            GATE_MAC(W1, xh);
        }
    } else if (t > 0) {
        const float* __restrict__ W0 = g_buf + G0H + (size_t)n * 16384;
        GATE_MAC(W0, xh);
    }
#undef GATE_MAC

    if (oh == 0) {
        size_t ZHoff = lay ? OFF_ZH1 : OFF_ZH0;
        #pragma unroll
        for (int j = 0; j < 4; j++) {
            int bg = bh * 16 + bl0 + j;
            float zz = 1.f / (1.f + expf(-acc[j]));
            float hv = (t == 0) ? 0.f : xh[(bl0 + j) * 128 + o];
            g_buf[ZHoff + (size_t)n * 2048 + (size_t)bg * 64 + o] = zz * hv;
        }
    } else {
        size_t Roff = lay ? OFF_R1 : OFF_R0;
        #pragma unroll
        for (int j = 0; j < 4; j++) {
            int bg = bh * 16 + bl0 + j;
            float r = 1.f / (1.f + expf(-acc[j]));
            g_buf[Roff + (size_t)n * 2048 + (size_t)bg * 64 + o] = r;
        }
    }
}

__device__ __forceinline__ void upd_item(int s, int it, float* smem, int tid) {
    int half = (it >= 614) ? 1 : 0;
    int idx0 = it - half * 614;
    int lay = (idx0 >= NN) ? 1 : 0;
    int n = idx0 - lay * NN;
    int t = lay ? (s - 1) : s;
    if (t < 0 || t >= TT) return;
    float* xh = smem;                        // [16][128]
    float* xx = smem + 2048;                 // [16][128]
    size_t ZHoff = lay ? OFF_ZH1 : OFF_ZH0;
    size_t Aoff  = lay ? OFF_AGG1B : OFF_AGG0B;   // r21: reads mode1 dbuf
    __syncthreads();
    for (int idx = tid; idx < 2048; idx += 256) {
        int bl = idx >> 7, c = idx & 127;
        int bg = half * 16 + bl;
        float v = (c < 64) ? g_buf[ZHoff + (size_t)n * 2048 + bg * 64 + c]
                           : g_buf[Aoff + (size_t)n * 2048 + bg * 64 + (c - 64)];
        xh[idx] = v;
    }
    if (lay) {
        size_t pb = ((size_t)t * NN + n) * 2048;
        for (int idx = tid; idx < 2048; idx += 256) {
            int bl = idx >> 7, c = idx & 127;
            int bg = half * 16 + bl;
            float v = (c < 64) ? g_buf[OFF_OUT0 + pb + bg * 64 + c]
                               : g_buf[OFF_AX1 + pb + bg * 64 + (c - 64)];
            xx[idx] = v;
        }
    }
    __syncthreads();
    int o = tid & 63, bl0 = (tid >> 6) * 4;
    size_t pbase = ((size_t)t * NN + n) * 32;
    float acc[4];
    if (lay) {
        float b0 = g_buf[BU1 + (size_t)n * 64 + o];
        #pragma unroll
        for (int j = 0; j < 4; j++) acc[j] = b0;
    } else {
        #pragma unroll
        for (int j = 0; j < 4; j++)
            acc[j] = g_buf[OFF_UXP + (pbase + half * 16 + bl0 + j) * 64 + o];
    }

#define UPD_MAC(WP, XP)                                                        \
    _Pragma("unroll 2")                                                        \
    for (int kq = 0; kq < 128; kq += 4) {                                      \
        float w0 = (WP)[(kq + 0) * 64 + o];                                    \
        float w1 = (WP)[(kq + 1) * 64 + o];                                    \
        float w2 = (WP)[(kq + 2) * 64 + o];                                    \
        float w3 = (WP)[(kq + 3) * 64 + o];                                    \
        _Pragma("unroll")                                                      \
        for (int j = 0; j < 4; j++) {                                          \
            float4 xv = *(const float4*)&(XP)[(bl0 + j) * 128 + kq];           \
            acc[j] += xv.x * w0 + xv.y * w1 + xv.z * w2 + xv.w * w3;           \
        }                                                                      \
    }

    if (lay) {
        const float* __restrict__ W0 = g_buf + U1X + (size_t)n * 8192;
        UPD_MAC(W0, xx);
        if (t > 0) {
            const float* __restrict__ W1 = g_buf + U1H + (size_t)n * 8192;
            UPD_MAC(W1, xh);
        }
    } else if (t > 0) {
        const float* __restrict__ W0 = g_buf + U0H + (size_t)n * 8192;
        UPD_MAC(W0, xh);
    }
#undef UPD_MAC

    size_t Hoff = lay ? OFF_H1 : OFF_H0;
    size_t Roff = lay ? OFF_R1 : OFF_R0;
    #pragma unroll
    for (int j = 0; j < 4; j++) {
        int bg = half * 16 + bl0 + j;
        size_t base = (size_t)n * 2048 + (size_t)bg * 64 + o;
        float hc = tanhf(acc[j]);
        float r = g_buf[Roff + base];
        float hold = (t == 0) ? 0.f : g_buf[Hoff + base];
        float hn = r * hold + (1.f - r) * hc;
        g_buf[Hoff + base] = hn;
        if (!lay) g_buf[OFF_OUT0 + (pbase + bg) * 64 + o] = hn;
    }
}

// ---------------- attention device fn (r13 body, flat smem) ----------------
// smem: x 3072 | kk 3072 | vv 3072 | q 256 | o1 256 | sc 192 | aw 192 = 10112
__device__ __forceinline__ void attn_dev(int ab, float* smem, int tid) {
    int wid = tid >> 6;
    int lane = tid & 63;
    int g = ab * 4 + wid;
    int b = g / NN, n = g - b * NN;
    float* x  = smem;
    float* kk = smem + 3072;
    float* vv = smem + 6144;
    float* q  = smem + 9216;
    float* o1 = smem + 9472;
    float* sc = smem + 9728;
    float* aw = smem + 9920;
    float* xw = x  + wid * (TT * HH);
    float* kw = kk + wid * (TT * HH);
    float* vw = vv + wid * (TT * HH);
    float mw = g_buf[S_MLW + lane];
    float mb = g_buf[S_MLB + lane];
    #pragma unroll
    for (int tt = 0; tt < TT; tt++) {
        float s = g_buf[S_SRC + ((size_t)b * TT + tt) * NN + n];
        xw[tt * HH + lane] = s * mw + mb + g_buf[OFF_PE + tt * HH + lane];
    }
    __syncthreads();
    float ka[TT], va[TT];
    #pragma unroll
    for (int tt = 0; tt < TT; tt++) { ka[tt] = g_buf[S_BK + lane]; va[tt] = g_buf[S_BV + lane]; }
    float qa = g_buf[S_BQ + lane];
    for (int i0 = 0; i0 < HH; i0 += 4) {
        float wk0 = g_buf[S_WK + (i0 + 0) * HH + lane];
        float wk1 = g_buf[S_WK + (i0 + 1) * HH + lane];
        float wk2 = g_buf[S_WK + (i0 + 2) * HH + lane];
        float wk3 = g_buf[S_WK + (i0 + 3) * HH + lane];
        float wv0 = g_buf[S_WV + (i0 + 0) * HH + lane];
        float wv1 = g_buf[S_WV + (i0 + 1) * HH + lane];
        float wv2 = g_buf[S_WV + (i0 + 2) * HH + lane];
        float wv3 = g_buf[S_WV + (i0 + 3) * HH + lane];
        float wq0 = g_buf[S_WQ + (i0 + 0) * HH + lane];
        float wq1 = g_buf[S_WQ + (i0 + 1) * HH + lane];
        float wq2 = g_buf[S_WQ + (i0 + 2) * HH + lane];
        float wq3 = g_buf[S_WQ + (i0 + 3) * HH + lane];
        float4 xq = *(const float4*)&xw[(TT - 1) * HH + i0];
        qa += xq.x * wq0 + xq.y * wq1 + xq.z * wq2 + xq.w * wq3;
        #pragma unroll
        for (int tt = 0; tt < TT; tt++) {
            float4 xv4 = *(const float4*)&xw[tt * HH + i0];   // broadcast b128
            ka[tt] += xv4.x * wk0 + xv4.y * wk1 + xv4.z * wk2 + xv4.w * wk3;
            va[tt] += xv4.x * wv0 + xv4.y * wv1 + xv4.z * wv2 + xv4.w * wv3;
        }
    }
    #pragma unroll
    for (int tt = 0; tt < TT; tt++) { kw[tt * HH + lane] = ka[tt]; vw[tt * HH + lane] = va[tt]; }
    q[wid * HH + lane] = qa;
    __syncthreads();
    if (lane < HEADS * TT) {
        int head = lane / TT, ts = lane - head * TT;
        float s = 0.f;
        #pragma unroll
        for (int d = 0; d < HD; d++) s += q[wid * HH + head * HD + d] * kw[ts * HH + head * HD + d];
        sc[wid * 48 + head * TT + ts] = s * 0.25f;
    }
    __syncthreads();
    if (lane < HEADS * TT) {
        int head = lane / TT, ts = lane - head * TT;
        float mx = -1e30f;
        #pragma unroll
        for (int j = 0; j < TT; j++) mx = fmaxf(mx, sc[wid * 48 + head * TT + j]);
        float sm = 0.f;
        #pragma unroll
        for (int j = 0; j < TT; j++) sm += expf(sc[wid * 48 + head * TT + j] - mx);
        aw[wid * 48 + head * TT + ts] = expf(sc[wid * 48 + head * TT + ts] - mx) / sm;
    }
    __syncthreads();
    int head = lane >> 4;
    float oa = 0.f;
    #pragma unroll
    for (int tt = 0; tt < TT; tt++) oa += aw[wid * 48 + head * TT + tt] * vw[tt * HH + lane];
    o1[wid * HH + lane] = oa;
    __syncthreads();
    float acc = g_buf[S_BO + lane];
    for (int i0 = 0; i0 < HH; i0 += 4) {
        float w0 = g_buf[S_WO + (i0 + 0) * HH + lane];
        float w1 = g_buf[S_WO + (i0 + 1) * HH + lane];
        float w2 = g_buf[S_WO + (i0 + 2) * HH + lane];
        float w3 = g_buf[S_WO + (i0 + 3) * HH + lane];
        float4 ov = *(const float4*)&o1[wid * HH + i0];
        acc += ov.x * w0 + ov.y * w1 + ov.z * w2 + ov.w * w3;
    }
    float res = xw[(TT - 1) * HH + lane] + acc;
    float mean = wave_sum(res) * (1.f / 64.f);
    float dv = res - mean;
    float var = wave_sum(dv * dv) * (1.f / 64.f);
    float ln = dv * rsqrtf(var + 1e-5f) * g_buf[S_L1G + lane] + g_buf[S_L1B + lane];
    g_buf[OFF_OLN + ((size_t)b * NN + n) * HH + lane] = ln;
}

// ---------------- FFN device fn (r13 body, flat smem) ----------------
// smem: ox 512 | hid 8192 = 8704
__device__ __forceinline__ void ffn_dev(int tok0, float* smem, int tid) {
    int lane = tid & 63, wvid = tid >> 6;
    float* ox = smem;
    float* hid = smem + 512;
    for (int idx = tid; idx < 8 * HH; idx += 256) {
        int tk = idx >> 6, hh = idx & 63;
        ox[tk * HH + hh] = g_buf[OFF_OLN + (size_t)(tok0 + tk) * HH + hh];
    }
    __syncthreads();
    {
        float acc[4][8];
        #pragma unroll
        for (int p = 0; p < 4; p++) {
            float bj = g_buf[S_FB1 + tid + 256 * p];
            #pragma unroll
            for (int tk = 0; tk < 8; tk++) acc[p][tk] = bj;
        }
        for (int i0 = 0; i0 < HH; i0 += 4) {
            float w1r[4][4];
            #pragma unroll
            for (int qq = 0; qq < 4; qq++)
                #pragma unroll
                for (int p = 0; p < 4; p++)
                    w1r[p][qq] = g_buf[S_FW1 + (size_t)(i0 + qq) * 1024 + tid + 256 * p];
            #pragma unroll
            for (int tk = 0; tk < 8; tk++) {
                float4 xo = *(const float4*)&ox[tk * HH + i0];
                const float* xp = (const float*)&xo;
                #pragma unroll
                for (int p = 0; p < 4; p++)
                    acc[p][tk] += xp[0] * w1r[p][0] + xp[1] * w1r[p][1]
                                + xp[2] * w1r[p][2] + xp[3] * w1r[p][3];
            }
        }
        #pragma unroll
        for (int p = 0; p < 4; p++)
            #pragma unroll
            for (int tk = 0; tk < 8; tk++)
                hid[tk * 1024 + tid + 256 * p] = fmaxf(acc[p][tk], 0.f);
    }
    __syncthreads();
    float pa[8], pb[8];
    #pragma unroll
    for (int tk = 0; tk < 8; tk++) { pa[tk] = 0.f; pb[tk] = 0.f; }
    {
        int jbase = wvid * 256;
        #pragma unroll 2
        for (int j4 = 0; j4 < 256; j4 += 4) {
            int j0 = jbase + j4;
            float w0 = g_buf[S_FW2 + (size_t)(j0 + 0) * HH + lane];
            float w1 = g_buf[S_FW2 + (size_t)(j0 + 1) * HH + lane];
            float w2 = g_buf[S_FW2 + (size_t)(j0 + 2) * HH + lane];
            float w3 = g_buf[S_FW2 + (size_t)(j0 + 3) * HH + lane];
            #pragma unroll
            for (int tk = 0; tk < 8; tk++) {
                float4 h4 = *(const float4*)&hid[tk * 1024 + j0];
                pa[tk] += h4.x * w0 + h4.y * w1;
                pb[tk] += h4.z * w2 + h4.w * w3;
            }
        }
    }
    __syncthreads();
    {
        float* rp = hid;                   // reuse as red[4][8][64]
        #pragma unroll
        for (int tk = 0; tk < 8; tk++)
            rp[(wvid * 8 + tk) * 64 + lane] = pa[tk] + pb[tk];
    }
    __syncthreads();
    int tk = wvid, hh = lane;
    float acc0 = g_buf[S_FB2 + hh], acc1 = acc0;
    {
        const float* rp = hid;
        #pragma unroll
        for (int w = 0; w < 4; w++) {
            acc0 += rp[(w * 8 + tk) * 64 + hh];
            acc1 += rp[(w * 8 + tk + 4) * 64 + hh];
        }
    }
    #pragma unroll
    for (int ph = 0; ph < 2; ph++) {
        int tkk = tk + 4 * ph;
        float res = ox[tkk * HH + hh] + (ph ? acc1 : acc0);
        float mean = wave_sum(res) * (1.f / 64.f);
        float dv = res - mean;
        float var = wave_sum(dv * dv) * (1.f / 64.f);
        float ln = dv * rsqrtf(var + 1e-5f) * g_buf[S_L2G + hh] + g_buf[S_L2B + hh];
        g_buf[OFF_O2 + (size_t)(tok0 + tkk) * HH + hh] = ln;
    }
}

// ---------------- chain kernels (r22 structure) ----------------
__global__ __launch_bounds__(256) void k_agg0(int s) {           // grid 640
    __shared__ float smem[6272];
    agg_item(s, 0, blockIdx.x, smem, threadIdx.x);
}
__global__ __launch_bounds__(256) void k_agg0Attn(int s) {       // grid 640+2456 (s=1)
    __shared__ float smem[10112];
    if (blockIdx.x < 640) agg_item(s, 0, blockIdx.x, smem, threadIdx.x);
    else                  attn_dev(blockIdx.x - 640, smem, threadIdx.x);
}
__global__ __launch_bounds__(256) void k_agg0Ffn(int s) {        // grid 640+1228 (s=2)
    __shared__ float smem[8704];
    if (blockIdx.x < 640) agg_item(s, 0, blockIdx.x, smem, threadIdx.x);
    else                  ffn_dev((blockIdx.x - 640) * 8, smem, threadIdx.x);
}
__global__ __launch_bounds__(256) void k_gateZ(int s) {          // grid 1228 (oh=0)
    __shared__ float smem[4096];
    gate_item2(s, blockIdx.x, smem, threadIdx.x);
}
__global__ __launch_bounds__(256) void k_gateAll(int s) {        // grid 2456 (s=0)
    __shared__ float smem[4096];
    gate_item2(s, blockIdx.x, smem, threadIdx.x);
}
__global__ __launch_bounds__(256) void k_mix(int s) {            // grid 640+1228: agg1 || gateR
    __shared__ float smem[6272];
    if (blockIdx.x < 640) agg_item(s, 1, blockIdx.x, smem, threadIdx.x);
    else                  gate_item2(s, 1228 + (blockIdx.x - 640), smem, threadIdx.x);
}
__global__ __launch_bounds__(256) void k_upd(int s) {            // grid 1228
    __shared__ float smem[4096];
    upd_item(s, blockIdx.x, smem, threadIdx.x);
}

// ---------------- final combine + horizon conv (layer-1 h is OFF_H1) ----------------
__global__ void k_final(void* out) {
    int n = blockIdx.x, b = blockIdx.y;
    int h = threadIdx.x;
    __shared__ float comb[HH];
    comb[h] = g_buf[OFF_H1 + ((size_t)n * 32 + b) * 64 + h] * g_buf[S_WS + n * HH + h]
            + g_buf[OFF_O2 + ((size_t)b * NN + n) * 64 + h] * g_buf[S_WT + n * HH + h];
    __syncthreads();
    if (h < HORIZON) {
        float acc = g_buf[S_CB + h];
        #pragma unroll
        for (int i = 0; i < HH; i++) acc += comb[i] * g_buf[S_CW + h * HH + i];
        size_t oi = ((size_t)b * HORIZON + h) * NN + n;
        if (g_flag) ((bf16*)out)[oi] = __float2bfloat16(acc);
        else        ((float*)out)[oi] = acc;
    }
}

extern "C" void kernel_launch(void* const* d_in, const int* in_sizes, int n_in,
                              void* d_out, int out_size, void* d_ws, size_t ws_size,
                              hipStream_t stream) {
    PtrPack pk;
    for (int i = 0; i < 32; i++) pk.p[i] = d_in[i];

    k_detect<<<1, 64, 0, stream>>>(d_in[1]);
    k_ingest<<<4133, 256, 0, stream>>>(pk);
    k_adj<<<NN, 512, 0, stream>>>();
    k_nodew_all<<<22335, 256, 0, stream>>>();
    k_pe<<<1, 768, 0, stream>>>();
    k_ax0<<<dim3(39, 12), 256, 0, stream>>>();
    k_xprep0<<<dim3(12, NN), 256, 0, stream>>>();

    // ---- supersteps: agg0(+attn/+ffn) -> gateZ -> {agg1 || gateR} -> upd ----
    k_gateAll<<<2456, 256, 0, stream>>>(0);
    k_upd<<<1228, 256, 0, stream>>>(0);
    for (int s = 1; s <= TT; s++) {
        if (s == 1)      k_agg0Attn<<<3096, 256, 0, stream>>>(s);  // + attention branch
        else if (s == 2) k_agg0Ffn<<<1868, 256, 0, stream>>>(s);   // + FFN branch
        else             k_agg0<<<640, 256, 0, stream>>>(s);
        k_gateZ<<<1228, 256, 0, stream>>>(s);   // z outputs, batch-split
        k_mix  <<<1868, 256, 0, stream>>>(s);   // A@ZH -> AGG*B || gate r-half
        k_upd  <<<1228, 256, 0, stream>>>(s);
    }

    // ---- combine + conv (needs H1 from upd(12) and O2 from ffn@s=2) ----
    k_final<<<dim3(NN, BB), 64, 0, stream>>>(d_out);
}